// Round 11
// baseline (2007.641 us; speedup 1.0000x reference)
//
#include <hip/hip_runtime.h>
#include <cstdint>
#include <cstddef>

#define D_MODEL   3072
#define D_SPARSE  24576
#define N_TOKENS  8192
#define K_SPARSE  128
#define NT        (D_MODEL/64)   // 48 K-tiles of BK=64

typedef _Float16 half8  __attribute__((ext_vector_type(8)));
typedef _Float16 half4v __attribute__((ext_vector_type(4)));
typedef float    f32x4  __attribute__((ext_vector_type(4)));

#define SCALE_A   64.0f
#define SCALE_B   4096.0f
#define INV_SCALE (1.0f/(SCALE_A*SCALE_B))   // 2^-18, exact

#define DELTA  6.0e-3f
#define MAXU   256
#define CAP    1536     // mem-path compact capacity
#define RAWCAP 768      // fused-path raw list capacity (mean ~560, +9 sigma)
#define GUARD  2.0f     // prefilter threshold; 128th value ~2.56
#define SEG    4096     // mem-path topk_write span per block
#define CNTSTR 16       // counts stride in ints (64B -> one row per cache line)
#define LCAP   24       // per-block per-row LDS list cap (mean 5.9, +7.4 sigma)

#define GLOBAL_AS(p) ((const __attribute__((address_space(1))) uint32_t*)(p))
#define LDS_AS(p)    ((__attribute__((address_space(3))) uint32_t*)(p))

// ---------- converts: fp32 -> fp16 (single hi limb), scaled ----------
__global__ void convert_h_kernel(const float* __restrict__ h,
                                 const float* __restrict__ pre_bias,
                                 _Float16* __restrict__ A1) {
  const int total4 = N_TOKENS * (D_MODEL/4);
  for (int m = blockIdx.x*blockDim.x + threadIdx.x; m < total4; m += gridDim.x*blockDim.x) {
    const int c4 = m % (D_MODEL/4);
    const float4 v  = reinterpret_cast<const float4*>(h)[m];
    const float4 pb = reinterpret_cast<const float4*>(pre_bias)[c4];
    half4v o;
    o[0] = (_Float16)((v.x-pb.x)*SCALE_A); o[1] = (_Float16)((v.y-pb.y)*SCALE_A);
    o[2] = (_Float16)((v.z-pb.z)*SCALE_A); o[3] = (_Float16)((v.w-pb.w)*SCALE_A);
    reinterpret_cast<half4v*>(A1)[m] = o;
  }
}

__global__ void convert_w_kernel(const float* __restrict__ W,
                                 _Float16* __restrict__ B1) {
  const int total4 = D_SPARSE * (D_MODEL/4);
  for (int m = blockIdx.x*blockDim.x + threadIdx.x; m < total4; m += gridDim.x*blockDim.x) {
    const float4 v = reinterpret_cast<const float4*>(W)[m];
    half4v o;
    o[0] = (_Float16)(v.x*SCALE_B); o[1] = (_Float16)(v.y*SCALE_B);
    o[2] = (_Float16)(v.z*SCALE_B); o[3] = (_Float16)(v.w*SCALE_B);
    reinterpret_cast<half4v*>(B1)[m] = o;
  }
}

__global__ void zero_counts_kernel(int* __restrict__ counts) {
  const int i = blockIdx.x * blockDim.x + threadIdx.x;
  if (i < N_TOKENS * CNTSTR) counts[i] = 0;
}

// ---------- 256x256 8-phase GEMM (round-9 verified schedule) ----------
// Fused epilogue: compact >GUARD into raw lists (LDS-aggregated) AND zero-fill
// the C tile (zeros hidden under compute; final scatter kernel fills 128/row).
__global__ __launch_bounds__(512) void gemm_kernel(const _Float16* __restrict__ A1,
                                                   const _Float16* __restrict__ B1,
                                                   const float* __restrict__ enc_bias,
                                                   float* __restrict__ C,
                                                   int2* __restrict__ raw,
                                                   int* __restrict__ counts,
                                                   int fused) {
  __shared__ _Float16 As[2][2][256][32];   // 64 KiB (reused as epilogue scratch)
  __shared__ _Float16 Bs[2][2][256][32];   // 64 KiB

  const int nwg = (N_TOKENS/256) * (D_SPARSE/256);      // 3072
  const int cpx = nwg / 8;
  const int swz = (blockIdx.x & 7) * cpx + (blockIdx.x >> 3);
  const int bm = swz / (D_SPARSE/256);
  const int bn = swz % (D_SPARSE/256);

  const int tid  = threadIdx.x;
  const int lane = tid & 63;
  const int wid  = tid >> 6;
  const int wm = wid >> 2;
  const int wn = wid & 3;

  const int r16   = lane & 15;
  const int khalf = lane >> 4;
  const int slot8 = ((khalf ^ ((r16 >> 1) & 3)) << 3);   // p(r)=(r>>1)&3 (conflict-free, r6-verified)

  const _Float16* gA = A1 + (size_t)bm * 256 * D_MODEL;
  const _Float16* gB = B1 + (size_t)bn * 256 * D_MODEL;

  const int c0 = tid;
  const int r0 = c0 >> 2;
  const int s0 = (c0 & 3) ^ ((r0 >> 1) & 3);
  const size_t goff0 = (size_t)r0 * D_MODEL + s0 * 8;
  const size_t goff1 = goff0 + (size_t)128 * D_MODEL;
  const int ldsOff0 = wid * 512;
  const int ldsOff1 = 4096 + wid * 512;

  #define STAGE(gsrc, lplane, kb) do { \
    __builtin_amdgcn_global_load_lds(GLOBAL_AS((gsrc) + goff0 + (kb)), LDS_AS((lplane) + ldsOff0), 16, 0, 0); \
    __builtin_amdgcn_global_load_lds(GLOBAL_AS((gsrc) + goff1 + (kb)), LDS_AS((lplane) + ldsOff1), 16, 0, 0); \
  } while (0)

  #define WAIT_VM8  asm volatile("s_waitcnt vmcnt(8)" ::: "memory")
  #define WAIT_LGKM asm volatile("s_waitcnt lgkmcnt(0)" ::: "memory")
  #define BAR()     __builtin_amdgcn_s_barrier()

  f32x4 acc[8][4] = {};
  half8 af[8], bf0, bf1;

  STAGE(gA, &As[0][0][0][0], 0);
  STAGE(gB, &Bs[0][0][0][0], 0);
  STAGE(gA, &As[0][1][0][0], 32);
  STAGE(gB, &Bs[0][1][0][0], 32);
  STAGE(gA, &As[1][0][0][0], 64);
  STAGE(gB, &Bs[1][0][0][0], 64);
  WAIT_VM8; BAR();

  #pragma unroll 1
  for (int t = 0; t < NT; ++t) {
    const int buf = t & 1, nbuf = buf ^ 1;
    const int kt1 = (t+1 < NT ? t+1 : NT-1) * 64;
    const int kt2 = (t+2 < NT ? t+2 : NT-1) * 64;
    const _Float16* Ap0 = &As[buf][0][0][0];
    const _Float16* Bp0 = &Bs[buf][0][0][0];
    const _Float16* Ap1 = &As[buf][1][0][0];
    const _Float16* Bp1 = &Bs[buf][1][0][0];

    #pragma unroll
    for (int mi = 0; mi < 8; ++mi)
      af[mi] = *reinterpret_cast<const half8*>(Ap0 + (wm*128 + mi*16 + r16)*32 + slot8);
    bf0 = *reinterpret_cast<const half8*>(Bp0 + (wn*64 +  0 + r16)*32 + slot8);
    bf1 = *reinterpret_cast<const half8*>(Bp0 + (wn*64 + 16 + r16)*32 + slot8);
    STAGE(gA, &As[nbuf][1][0][0], kt1 + 32);
    BAR(); WAIT_LGKM;
    __builtin_amdgcn_s_setprio(1);
    #pragma unroll
    for (int mi = 0; mi < 8; ++mi) {
      acc[mi][0] = __builtin_amdgcn_mfma_f32_16x16x32_f16(af[mi], bf0, acc[mi][0], 0, 0, 0);
      acc[mi][1] = __builtin_amdgcn_mfma_f32_16x16x32_f16(af[mi], bf1, acc[mi][1], 0, 0, 0);
    }
    __builtin_amdgcn_s_setprio(0);
    BAR();

    bf0 = *reinterpret_cast<const half8*>(Bp0 + (wn*64 + 32 + r16)*32 + slot8);
    bf1 = *reinterpret_cast<const half8*>(Bp0 + (wn*64 + 48 + r16)*32 + slot8);
    STAGE(gB, &Bs[nbuf][1][0][0], kt1 + 32);
    BAR(); WAIT_LGKM;
    __builtin_amdgcn_s_setprio(1);
    #pragma unroll
    for (int mi = 0; mi < 8; ++mi) {
      acc[mi][2] = __builtin_amdgcn_mfma_f32_16x16x32_f16(af[mi], bf0, acc[mi][2], 0, 0, 0);
      acc[mi][3] = __builtin_amdgcn_mfma_f32_16x16x32_f16(af[mi], bf1, acc[mi][3], 0, 0, 0);
    }
    __builtin_amdgcn_s_setprio(0);
    WAIT_VM8; BAR();

    #pragma unroll
    for (int mi = 0; mi < 8; ++mi)
      af[mi] = *reinterpret_cast<const half8*>(Ap1 + (wm*128 + mi*16 + r16)*32 + slot8);
    bf0 = *reinterpret_cast<const half8*>(Bp1 + (wn*64 +  0 + r16)*32 + slot8);
    bf1 = *reinterpret_cast<const half8*>(Bp1 + (wn*64 + 16 + r16)*32 + slot8);
    STAGE(gA, &As[buf][0][0][0], kt2);
    BAR(); WAIT_LGKM;
    __builtin_amdgcn_s_setprio(1);
    #pragma unroll
    for (int mi = 0; mi < 8; ++mi) {
      acc[mi][0] = __builtin_amdgcn_mfma_f32_16x16x32_f16(af[mi], bf0, acc[mi][0], 0, 0, 0);
      acc[mi][1] = __builtin_amdgcn_mfma_f32_16x16x32_f16(af[mi], bf1, acc[mi][1], 0, 0, 0);
    }
    __builtin_amdgcn_s_setprio(0);
    BAR();

    bf0 = *reinterpret_cast<const half8*>(Bp1 + (wn*64 + 32 + r16)*32 + slot8);
    bf1 = *reinterpret_cast<const half8*>(Bp1 + (wn*64 + 48 + r16)*32 + slot8);
    STAGE(gB, &Bs[buf][0][0][0], kt2);
    BAR(); WAIT_LGKM;
    __builtin_amdgcn_s_setprio(1);
    #pragma unroll
    for (int mi = 0; mi < 8; ++mi) {
      acc[mi][2] = __builtin_amdgcn_mfma_f32_16x16x32_f16(af[mi], bf0, acc[mi][2], 0, 0, 0);
      acc[mi][3] = __builtin_amdgcn_mfma_f32_16x16x32_f16(af[mi], bf1, acc[mi][3], 0, 0, 0);
    }
    __builtin_amdgcn_s_setprio(0);
    WAIT_VM8; BAR();
  }

  asm volatile("s_waitcnt vmcnt(0) lgkmcnt(0)" ::: "memory");

  // epilogue: C/D layout col=lane&15, row=(lane>>4)*4+reg [m89-verified]
  const int row0 = bm*256 + wm*128 + khalf*4;
  const int col0 = bn*256 + wn*64 + r16;
  if (fused) {
    // --- zero-fill this block's C tile (hidden under epilogue; scatter fills later) ---
    {
      const float4 z = {0.0f, 0.0f, 0.0f, 0.0f};
      float4* ctile = reinterpret_cast<float4*>(C + (size_t)(bm*256) * D_SPARSE + bn*256);
      const size_t ld4 = D_SPARSE / 4;   // row stride in float4
      for (int i = tid; i < 256*64; i += 512)
        ctile[(size_t)(i >> 6) * ld4 + (i & 63)] = z;
    }
    // --- LDS-aggregated compaction: 1 global atomic per (row, block) ---
    __syncthreads();                                  // all LDS reads done; safe to reuse As/Bs
    int2* lbuf = (int2*)&As[0][0][0][0];              // 256 rows x LCAP entries = 48 KB
    int*  lcnt = (int*)&Bs[0][0][0][0];               // 256 ints
    for (int r = tid; r < 256; r += 512) lcnt[r] = 0;
    __syncthreads();

    const int lrow0 = wm*128 + khalf*4;
    #pragma unroll
    for (int ni = 0; ni < 4; ++ni) {
      const int col = col0 + ni*16;
      const float b = enc_bias[col];
      #pragma unroll
      for (int mi = 0; mi < 8; ++mi) {
        const int lrow = lrow0 + mi*16;
        #pragma unroll
        for (int r = 0; r < 4; ++r) {
          const float v = acc[mi][ni][r] * INV_SCALE + b;
          if (v > GUARD) {
            const int p = atomicAdd(&lcnt[lrow + r], 1);
            if (p < LCAP) lbuf[(lrow + r)*LCAP + p] = make_int2(col, __float_as_int(v));
            else {
              const int gp = atomicAdd(&counts[(bm*256 + lrow + r)*CNTSTR], 1);
              if (gp < RAWCAP) raw[(size_t)(bm*256 + lrow + r) * RAWCAP + gp] = make_int2(col, __float_as_int(v));
            }
          }
        }
      }
    }
    __syncthreads();

    if (tid < 256) {
      int lc = lcnt[tid]; if (lc > LCAP) lc = LCAP;
      if (lc > 0) {
        const int grow = bm*256 + tid;
        const int base = atomicAdd(&counts[grow*CNTSTR], lc);
        for (int i = 0; i < lc; ++i) {
          const int p = base + i;
          if (p < RAWCAP) raw[(size_t)grow * RAWCAP + p] = lbuf[tid*LCAP + i];
        }
      }
    }
  } else {
    #pragma unroll
    for (int ni = 0; ni < 4; ++ni) {
      const int col = col0 + ni*16;
      const float b = enc_bias[col];
      #pragma unroll
      for (int mi = 0; mi < 8; ++mi) {
        const int row = row0 + mi*16;
        #pragma unroll
        for (int r = 0; r < 4; ++r)
          C[(size_t)(row + r) * D_SPARSE + col] = acc[mi][ni][r] * INV_SCALE + b;
      }
    }
  }
  #undef STAGE
  #undef WAIT_VM8
  #undef WAIT_LGKM
  #undef BAR
}

// ---------- shared helpers ----------
__device__ __forceinline__ uint32_t f2key(float f) {
  uint32_t b = __float_as_uint(f);
  return (b & 0x80000000u) ? ~b : (b | 0x80000000u);
}
__device__ __forceinline__ float key2f(uint32_t k) {
  uint32_t b = (k & 0x80000000u) ? (k ^ 0x80000000u) : ~k;
  return __uint_as_float(b);
}
__device__ float preact_f32(int s, const float* __restrict__ hrow,
                            const float* __restrict__ pre_bias,
                            const float* __restrict__ W,
                            const float* __restrict__ enc_bias) {
  const float* wrow = W + (size_t)s * D_MODEL;
  float acc = 0.f;
  for (int k = 0; k < D_MODEL; ++k) acc += (hrow[k] - pre_bias[k]) * wrow[k];
  return acc + enc_bias[s];
}

// ---------- fused select: radix on compact raw list + fp64 rescue; GEMV fallback ----------
__global__ __launch_bounds__(256) void topk_select_fused(const int2* __restrict__ raw,
                                                         const int* __restrict__ counts,
                                                         const float* __restrict__ h,
                                                         const float* __restrict__ pre_bias,
                                                         const float* __restrict__ W,
                                                         const float* __restrict__ enc_bias,
                                                         int2* __restrict__ lists) {
  const int row = blockIdx.x;
  const int tid  = threadIdx.x;
  const int lane = tid & 63;
  const int wid  = tid >> 6;

  __shared__ float lv[RAWCAP];
  __shared__ int   li[RAWCAP];
  __shared__ int hist4[4][256];
  __shared__ int wsum[4];
  __shared__ int s_found, s_digit, s_rem, s_ucnt, s_emit;
  __shared__ int u_idx[MAXU];
  __shared__ double u_val[MAXU];
  __shared__ unsigned char u_sel[MAXU];

  const float* hrow = h + (size_t)row * D_MODEL;
  const int cntRaw = counts[row * CNTSTR];
  const int cnt = cntRaw < RAWCAP ? cntRaw : RAWCAP;
  bool mainok = (cntRaw >= K_SPARSE && cntRaw <= RAWCAP);
  float kth = 0.0f;

  if (mainok) {
    for (int e = tid; e < cnt; e += 256) {
      const int2 p = raw[(size_t)row * RAWCAP + e];
      li[e] = p.x; lv[e] = __int_as_float(p.y);
    }
    __syncthreads();
    uint32_t prefix = 0, pmask = 0;
    int remaining = K_SPARSE;
    for (int level = 0; level < 4; ++level) {
      const int shift = 24 - 8*level;
      #pragma unroll
      for (int w = 0; w < 4; ++w) hist4[w][tid] = 0;
      if (tid == 0) s_found = 1 << 30;
      __syncthreads();
      for (int e = tid; e < cnt; e += 256) {
        const uint32_t k = __float_as_uint(lv[e]);   // positive floats: raw bits monotone
        if ((k & pmask) == prefix) atomicAdd(&hist4[wid][(k >> shift) & 255], 1);
      }
      __syncthreads();
      const int bin = 255 - tid;
      const int cb = hist4[0][bin] + hist4[1][bin] + hist4[2][bin] + hist4[3][bin];
      int sc = cb;
      #pragma unroll
      for (int d = 1; d < 64; d <<= 1) {
        const int o = __shfl_up(sc, d, 64);
        if (lane >= d) sc += o;
      }
      if (lane == 63) wsum[wid] = sc;
      __syncthreads();
      int woff = 0;
      for (int w = 0; w < wid; ++w) woff += wsum[w];
      sc += woff;
      if (sc >= remaining) atomicMin(&s_found, tid);
      __syncthreads();
      if (tid == s_found) { s_digit = bin; s_rem = remaining - (sc - cb); }
      __syncthreads();
      prefix |= ((uint32_t)s_digit) << shift;
      pmask  |= 0xFFu << shift;
      remaining = s_rem;
      __syncthreads();
    }
    kth = __uint_as_float(prefix);
    if (!(kth - DELTA > GUARD)) mainok = false;   // window must stay inside list coverage
  }

  if (!mainok) {
    // exact fp32 on-the-fly radix (correctness escape; never taken on this data)
    uint32_t prefix = 0, pmask = 0;
    int remaining = K_SPARSE;
    for (int level = 0; level < 4; ++level) {
      const int shift = 24 - 8*level;
      #pragma unroll
      for (int w = 0; w < 4; ++w) hist4[w][tid] = 0;
      if (tid == 0) s_found = 1 << 30;
      __syncthreads();
      for (int j = 0; j < D_SPARSE/256; ++j) {
        const uint32_t k = f2key(preact_f32(tid + j*256, hrow, pre_bias, W, enc_bias));
        if ((k & pmask) == prefix) atomicAdd(&hist4[wid][(k >> shift) & 255], 1);
      }
      __syncthreads();
      const int bin = 255 - tid;
      const int cb = hist4[0][bin] + hist4[1][bin] + hist4[2][bin] + hist4[3][bin];
      int sc = cb;
      #pragma unroll
      for (int d = 1; d < 64; d <<= 1) {
        const int o = __shfl_up(sc, d, 64);
        if (lane >= d) sc += o;
      }
      if (lane == 63) wsum[wid] = sc;
      __syncthreads();
      int woff = 0;
      for (int w = 0; w < wid; ++w) woff += wsum[w];
      sc += woff;
      if (sc >= remaining) atomicMin(&s_found, tid);
      __syncthreads();
      if (tid == s_found) { s_digit = bin; s_rem = remaining - (sc - cb); }
      __syncthreads();
      prefix |= ((uint32_t)s_digit) << shift;
      pmask  |= 0xFFu << shift;
      remaining = s_rem;
      __syncthreads();
    }
    kth = key2f(prefix);
  }

  const float thrHi = kth + DELTA;
  const float thrLo = kth - DELTA;
  int2* __restrict__ rowlist = lists + (size_t)row * K_SPARSE;

  if (tid == 0) { s_ucnt = 0; s_emit = 0; }
  __syncthreads();

  if (mainok) {
    for (int e = tid; e < cnt; e += 256) {
      const float x = lv[e];
      if (x > thrHi) {
        const int p = atomicAdd(&s_emit, 1);
        if (p < K_SPARSE) rowlist[p] = make_int2(li[e], __float_as_int(fmaxf(x, 0.0f)));
      } else if (x >= thrLo) {
        const int p = atomicAdd(&s_ucnt, 1);
        if (p < MAXU) u_idx[p] = li[e];
      }
    }
  } else {
    for (int j = 0; j < D_SPARSE/256; ++j) {
      const int s = tid + j*256;
      const float x = preact_f32(s, hrow, pre_bias, W, enc_bias);
      if (x > thrHi) {
        const int p = atomicAdd(&s_emit, 1);
        if (p < K_SPARSE) rowlist[p] = make_int2(s, __float_as_int(fmaxf(x, 0.0f)));
      } else if (x >= thrLo) {
        const int p = atomicAdd(&s_ucnt, 1);
        if (p < MAXU) u_idx[p] = s;
      }
    }
  }
  __syncthreads();

  const int nabove = s_emit;
  const int ucnt = s_ucnt < MAXU ? s_ucnt : MAXU;
  int m = K_SPARSE - nabove;
  if (m < 0) m = 0; if (m > ucnt) m = ucnt;

  for (int e = wid; e < ucnt; e += 4) {
    const int ci = u_idx[e];
    const float* wrow = W + (size_t)ci * D_MODEL;
    double s = 0.0;
    for (int k = lane; k < D_MODEL; k += 64)
      s += (double)(hrow[k] - pre_bias[k]) * (double)wrow[k];
    #pragma unroll
    for (int off = 32; off; off >>= 1) s += __shfl_down(s, off, 64);
    if (lane == 0) u_val[e] = s + (double)enc_bias[ci];
  }
  __syncthreads();

  if (tid == 0) {
    for (int e = 0; e < ucnt; ++e) u_sel[e] = 0;
    for (int t = 0; t < m; ++t) {
      int best = -1;
      for (int e = 0; e < ucnt; ++e) {
        if (u_sel[e]) continue;
        if (best < 0 || u_val[e] > u_val[best] ||
            (u_val[e] == u_val[best] && u_idx[e] < u_idx[best])) best = e;
      }
      if (best >= 0) u_sel[best] = 1;
    }
  }
  __syncthreads();

  for (int e = tid; e < ucnt; e += 256)
    if (u_sel[e]) {
      const int p = atomicAdd(&s_emit, 1);
      if (p < K_SPARSE) rowlist[p] = make_int2(u_idx[e], __float_as_int(fmaxf((float)u_val[e], 0.0f)));
    }
  __syncthreads();
  if (tid == 0)
    for (int p = s_emit; p < K_SPARSE; ++p) rowlist[p] = make_int2(-1, 0);
}

// ---------- mem-path select (round-6 verified; used when ws too small) ----------
__global__ __launch_bounds__(256) void topk_select_mem(const float* __restrict__ C,
                                                       const float* __restrict__ h,
                                                       const float* __restrict__ pre_bias,
                                                       const float* __restrict__ W,
                                                       const float* __restrict__ enc_bias,
                                                       int2* __restrict__ lists) {
  const int row = blockIdx.x;
  const float* __restrict__ Crow = C + (size_t)row * D_SPARSE;
  const int tid  = threadIdx.x;
  const int lane = tid & 63;
  const int wid  = tid >> 6;

  __shared__ float lv[CAP];
  __shared__ int   li[CAP];
  __shared__ int hist4[4][256];
  __shared__ int wsum[4];
  __shared__ int s_cnt, s_found, s_digit, s_rem, s_ucnt, s_emit;
  __shared__ int u_idx[MAXU];
  __shared__ double u_val[MAXU];
  __shared__ unsigned char u_sel[MAXU];

  if (tid == 0) s_cnt = 0;
  __syncthreads();

  for (int j = 0; j < 24; ++j) {
    const float4 v = reinterpret_cast<const float4*>(Crow)[tid + j*256];
    const int base = (tid + j*256) * 4;
    #pragma unroll
    for (int c = 0; c < 4; ++c) {
      const float x = (&v.x)[c];
      if (x > GUARD) {
        const int p = atomicAdd(&s_cnt, 1);
        if (p < CAP) { lv[p] = x; li[p] = base + c; }
      }
    }
  }
  __syncthreads();
  const int cnt = s_cnt;
  bool mainok = (cnt >= K_SPARSE && cnt <= CAP);
  float kth = 0.0f;

  if (mainok) {
    uint32_t prefix = 0, pmask = 0;
    int remaining = K_SPARSE;
    for (int level = 0; level < 4; ++level) {
      const int shift = 24 - 8*level;
      #pragma unroll
      for (int w = 0; w < 4; ++w) hist4[w][tid] = 0;
      if (tid == 0) s_found = 1 << 30;
      __syncthreads();
      for (int e = tid; e < cnt; e += 256) {
        const uint32_t k = __float_as_uint(lv[e]);
        if ((k & pmask) == prefix) atomicAdd(&hist4[wid][(k >> shift) & 255], 1);
      }
      __syncthreads();
      const int bin = 255 - tid;
      const int cb = hist4[0][bin] + hist4[1][bin] + hist4[2][bin] + hist4[3][bin];
      int sc = cb;
      #pragma unroll
      for (int d = 1; d < 64; d <<= 1) {
        const int o = __shfl_up(sc, d, 64);
        if (lane >= d) sc += o;
      }
      if (lane == 63) wsum[wid] = sc;
      __syncthreads();
      int woff = 0;
      for (int w = 0; w < wid; ++w) woff += wsum[w];
      sc += woff;
      if (sc >= remaining) atomicMin(&s_found, tid);
      __syncthreads();
      if (tid == s_found) { s_digit = bin; s_rem = remaining - (sc - cb); }
      __syncthreads();
      prefix |= ((uint32_t)s_digit) << shift;
      pmask  |= 0xFFu << shift;
      remaining = s_rem;
      __syncthreads();
    }
    kth = __uint_as_float(prefix);
    if (!(kth - DELTA > GUARD)) mainok = false;
  }

  if (!mainok) {
    uint32_t prefix = 0, pmask = 0;
    int remaining = K_SPARSE;
    for (int level = 0; level < 4; ++level) {
      const int shift = 24 - 8*level;
      #pragma unroll
      for (int w = 0; w < 4; ++w) hist4[w][tid] = 0;
      if (tid == 0) s_found = 1 << 30;
      __syncthreads();
      for (int j = 0; j < 24; ++j) {
        const float4 v = reinterpret_cast<const float4*>(Crow)[tid + j*256];
        #pragma unroll
        for (int c = 0; c < 4; ++c) {
          const uint32_t k = f2key((&v.x)[c]);
          if ((k & pmask) == prefix) atomicAdd(&hist4[wid][(k >> shift) & 255], 1);
        }
      }
      __syncthreads();
      const int bin = 255 - tid;
      const int cb = hist4[0][bin] + hist4[1][bin] + hist4[2][bin] + hist4[3][bin];
      int sc = cb;
      #pragma unroll
      for (int d = 1; d < 64; d <<= 1) {
        const int o = __shfl_up(sc, d, 64);
        if (lane >= d) sc += o;
      }
      if (lane == 63) wsum[wid] = sc;
      __syncthreads();
      int woff = 0;
      for (int w = 0; w < wid; ++w) woff += wsum[w];
      sc += woff;
      if (sc >= remaining) atomicMin(&s_found, tid);
      __syncthreads();
      if (tid == s_found) { s_digit = bin; s_rem = remaining - (sc - cb); }
      __syncthreads();
      prefix |= ((uint32_t)s_digit) << shift;
      pmask  |= 0xFFu << shift;
      remaining = s_rem;
      __syncthreads();
    }
    kth = key2f(prefix);
  }

  const float thrHi = kth + DELTA;
  const float thrLo = kth - DELTA;
  int2* __restrict__ rowlist = lists + (size_t)row * K_SPARSE;

  if (tid == 0) { s_ucnt = 0; s_emit = 0; }
  __syncthreads();

  if (mainok) {
    for (int e = tid; e < cnt; e += 256) {
      const float x = lv[e];
      if (x > thrHi) {
        const int p = atomicAdd(&s_emit, 1);
        if (p < K_SPARSE) rowlist[p] = make_int2(li[e], __float_as_int(fmaxf(x, 0.0f)));
      } else if (x >= thrLo) {
        const int p = atomicAdd(&s_ucnt, 1);
        if (p < MAXU) u_idx[p] = li[e];
      }
    }
  } else {
    for (int j = 0; j < 24; ++j) {
      const float4 v = reinterpret_cast<const float4*>(Crow)[tid + j*256];
      const int base = (tid + j*256) * 4;
      #pragma unroll
      for (int c = 0; c < 4; ++c) {
        const float x = (&v.x)[c];
        if (x > thrHi) {
          const int p = atomicAdd(&s_emit, 1);
          if (p < K_SPARSE) rowlist[p] = make_int2(base + c, __float_as_int(fmaxf(x, 0.0f)));
        } else if (x >= thrLo) {
          const int p = atomicAdd(&s_ucnt, 1);
          if (p < MAXU) u_idx[p] = base + c;
        }
      }
    }
  }
  __syncthreads();

  const int nabove = s_emit;
  const int ucnt = s_ucnt < MAXU ? s_ucnt : MAXU;
  int m = K_SPARSE - nabove;
  if (m < 0) m = 0; if (m > ucnt) m = ucnt;

  const float* hrow = h + (size_t)row * D_MODEL;
  for (int e = wid; e < ucnt; e += 4) {
    const int ci = u_idx[e];
    const float* wrow = W + (size_t)ci * D_MODEL;
    double s = 0.0;
    for (int k = lane; k < D_MODEL; k += 64)
      s += (double)(hrow[k] - pre_bias[k]) * (double)wrow[k];
    #pragma unroll
    for (int off = 32; off; off >>= 1) s += __shfl_down(s, off, 64);
    if (lane == 0) u_val[e] = s + (double)enc_bias[ci];
  }
  __syncthreads();

  if (tid == 0) {
    for (int e = 0; e < ucnt; ++e) u_sel[e] = 0;
    for (int t = 0; t < m; ++t) {
      int best = -1;
      for (int e = 0; e < ucnt; ++e) {
        if (u_sel[e]) continue;
        if (best < 0 || u_val[e] > u_val[best] ||
            (u_val[e] == u_val[best] && u_idx[e] < u_idx[best])) best = e;
      }
      if (best >= 0) u_sel[best] = 1;
    }
  }
  __syncthreads();

  for (int e = tid; e < ucnt; e += 256)
    if (u_sel[e]) {
      const int p = atomicAdd(&s_emit, 1);
      if (p < K_SPARSE) rowlist[p] = make_int2(u_idx[e], __float_as_int(fmaxf((float)u_val[e], 0.0f)));
    }
  __syncthreads();
  if (tid == 0)
    for (int p = s_emit; p < K_SPARSE; ++p) rowlist[p] = make_int2(-1, 0);
}

// ---------- fused-path final scatter: C already zeroed by gemm ----------
__global__ __launch_bounds__(128) void topk_scatter(const int2* __restrict__ lists,
                                                    float* __restrict__ C) {
  const int row = blockIdx.x;
  const int2 p = lists[(size_t)row * K_SPARSE + threadIdx.x];
  if (p.x >= 0) C[(size_t)row * D_SPARSE + p.x] = __int_as_float(p.y);
}

// ---------- mem-path top-k write: zero + scatter via LDS span ----------
__global__ __launch_bounds__(256) void topk_write(const int2* __restrict__ lists,
                                                  float* __restrict__ C) {
  const int nseg = D_SPARSE / SEG;              // 6
  const int row = blockIdx.x / nseg;
  const int seg = blockIdx.x % nseg;
  const int lo  = seg * SEG;
  const int tid = threadIdx.x;

  __shared__ float span[SEG];
  const float4 z = {0.0f, 0.0f, 0.0f, 0.0f};
  #pragma unroll
  for (int i = 0; i < SEG/1024; ++i)
    reinterpret_cast<float4*>(span)[tid + i*256] = z;
  __syncthreads();

  if (tid < K_SPARSE) {
    const int2 p = lists[(size_t)row * K_SPARSE + tid];
    const int off = p.x - lo;
    if (off >= 0 && off < SEG) span[off] = __int_as_float(p.y);
  }
  __syncthreads();

  float4* __restrict__ out4 = reinterpret_cast<float4*>(C + (size_t)row * D_SPARSE + lo);
  #pragma unroll
  for (int i = 0; i < SEG/1024; ++i)
    out4[tid + i*256] = reinterpret_cast<const float4*>(span)[tid + i*256];
}

// ---------------------------------------------------------------------------
extern "C" void kernel_launch(void* const* d_in, const int* in_sizes, int n_in,
                              void* d_out, int out_size, void* d_ws, size_t ws_size,
                              hipStream_t stream) {
  const float* h        = (const float*)d_in[0];
  const float* W        = (const float*)d_in[1];
  const float* pre_bias = (const float*)d_in[2];
  const float* enc_bias = (const float*)d_in[3];
  float* C = (float*)d_out;

  const size_t a1_bytes  = (size_t)N_TOKENS * D_MODEL * sizeof(_Float16);   // 50.3 MB
  const size_t b1_bytes  = (size_t)D_SPARSE * D_MODEL * sizeof(_Float16);   // 151.0 MB
  const size_t raw_bytes = (size_t)N_TOKENS * RAWCAP * sizeof(int2);        // 50.3 MB
  const size_t cnt_bytes = (size_t)N_TOKENS * CNTSTR * sizeof(int);         // 512 KB
  const size_t fin_bytes = (size_t)N_TOKENS * K_SPARSE * sizeof(int2);      // 8 MB
  if (ws_size < a1_bytes + b1_bytes) return;

  char* base = (char*)d_ws;
  _Float16* A1 = (_Float16*)base;
  _Float16* B1 = (_Float16*)(base + a1_bytes);

  const bool fused = ws_size >= a1_bytes + b1_bytes + raw_bytes + cnt_bytes + fin_bytes;
  int2* raw    = (int2*)(base + a1_bytes + b1_bytes);
  int*  counts = (int*)(base + a1_bytes + b1_bytes + raw_bytes);
  int2* fin    = fused ? (int2*)(base + a1_bytes + b1_bytes + raw_bytes + cnt_bytes)
                       : (int2*)base;   // mem path: A1 region is dead post-GEMM

  convert_h_kernel<<<2048, 256, 0, stream>>>(h, pre_bias, A1);
  convert_w_kernel<<<4096, 256, 0, stream>>>(W, B1);
  if (fused) zero_counts_kernel<<<(N_TOKENS*CNTSTR + 255)/256, 256, 0, stream>>>(counts);
  gemm_kernel<<<(N_TOKENS/256) * (D_SPARSE/256), 512, 0, stream>>>(
      A1, B1, enc_bias, C, raw, counts, fused ? 1 : 0);
  if (fused) {
    topk_select_fused<<<N_TOKENS, 256, 0, stream>>>(raw, counts, h, pre_bias, W, enc_bias, fin);
    topk_scatter<<<N_TOKENS, 128, 0, stream>>>(fin, C);
  } else {
    topk_select_mem<<<N_TOKENS, 256, 0, stream>>>(C, h, pre_bias, W, enc_bias, fin);
    topk_write<<<N_TOKENS * (D_SPARSE/SEG), 256, 0, stream>>>(fin, C);
  }
}

// Round 12
// 1909.456 us; speedup vs baseline: 1.0514x; 1.0514x over previous
//
#include <hip/hip_runtime.h>
#include <cstdint>
#include <cstddef>

#define D_MODEL   3072
#define D_SPARSE  24576
#define N_TOKENS  8192
#define K_SPARSE  128
#define NT        (D_MODEL/64)   // 48 K-tiles of BK=64

typedef _Float16 half8  __attribute__((ext_vector_type(8)));
typedef _Float16 half4v __attribute__((ext_vector_type(4)));
typedef float    f32x4  __attribute__((ext_vector_type(4)));

#define SCALE_A   64.0f
#define SCALE_B   4096.0f
#define INV_SCALE (1.0f/(SCALE_A*SCALE_B))   // 2^-18, exact

#define DELTA  6.0e-3f
#define MAXU   256
#define CAP    1536     // mem-path compact capacity
#define RAWCAP 768      // fused-path raw list capacity (mean ~560, +9 sigma)
#define GUARD  2.0f     // prefilter threshold; 128th value ~2.56
#define SEG    4096     // topk_write span per block
#define CNTSTR 16       // counts stride in ints (64B -> one row per cache line)
#define LCAP   24       // per-block per-row LDS list cap (mean 5.9, +7.4 sigma)

#define GLOBAL_AS(p) ((const __attribute__((address_space(1))) uint32_t*)(p))
#define LDS_AS(p)    ((__attribute__((address_space(3))) uint32_t*)(p))

// ---------- converts: fp32 -> fp16 (single hi limb), scaled ----------
__global__ void convert_h_kernel(const float* __restrict__ h,
                                 const float* __restrict__ pre_bias,
                                 _Float16* __restrict__ A1) {
  const int total4 = N_TOKENS * (D_MODEL/4);
  for (int m = blockIdx.x*blockDim.x + threadIdx.x; m < total4; m += gridDim.x*blockDim.x) {
    const int c4 = m % (D_MODEL/4);
    const float4 v  = reinterpret_cast<const float4*>(h)[m];
    const float4 pb = reinterpret_cast<const float4*>(pre_bias)[c4];
    half4v o;
    o[0] = (_Float16)((v.x-pb.x)*SCALE_A); o[1] = (_Float16)((v.y-pb.y)*SCALE_A);
    o[2] = (_Float16)((v.z-pb.z)*SCALE_A); o[3] = (_Float16)((v.w-pb.w)*SCALE_A);
    reinterpret_cast<half4v*>(A1)[m] = o;
  }
}

__global__ void convert_w_kernel(const float* __restrict__ W,
                                 _Float16* __restrict__ B1) {
  const int total4 = D_SPARSE * (D_MODEL/4);
  for (int m = blockIdx.x*blockDim.x + threadIdx.x; m < total4; m += gridDim.x*blockDim.x) {
    const float4 v = reinterpret_cast<const float4*>(W)[m];
    half4v o;
    o[0] = (_Float16)(v.x*SCALE_B); o[1] = (_Float16)(v.y*SCALE_B);
    o[2] = (_Float16)(v.z*SCALE_B); o[3] = (_Float16)(v.w*SCALE_B);
    reinterpret_cast<half4v*>(B1)[m] = o;
  }
}

__global__ void zero_counts_kernel(int* __restrict__ counts) {
  const int i = blockIdx.x * blockDim.x + threadIdx.x;
  if (i < N_TOKENS * CNTSTR) counts[i] = 0;
}

// ---------- 256x256 8-phase GEMM (round-9 verified schedule; best measured) ----------
__global__ __launch_bounds__(512) void gemm_kernel(const _Float16* __restrict__ A1,
                                                   const _Float16* __restrict__ B1,
                                                   const float* __restrict__ enc_bias,
                                                   float* __restrict__ C,
                                                   int2* __restrict__ raw,
                                                   int* __restrict__ counts,
                                                   int fused) {
  __shared__ _Float16 As[2][2][256][32];   // 64 KiB (reused as epilogue scratch)
  __shared__ _Float16 Bs[2][2][256][32];   // 64 KiB

  const int nwg = (N_TOKENS/256) * (D_SPARSE/256);      // 3072
  const int cpx = nwg / 8;
  const int swz = (blockIdx.x & 7) * cpx + (blockIdx.x >> 3);
  const int bm = swz / (D_SPARSE/256);
  const int bn = swz % (D_SPARSE/256);

  const int tid  = threadIdx.x;
  const int lane = tid & 63;
  const int wid  = tid >> 6;
  const int wm = wid >> 2;
  const int wn = wid & 3;

  const int r16   = lane & 15;
  const int khalf = lane >> 4;
  const int slot8 = ((khalf ^ ((r16 >> 1) & 3)) << 3);   // p(r)=(r>>1)&3 (conflict-free, r6-verified)

  const _Float16* gA = A1 + (size_t)bm * 256 * D_MODEL;
  const _Float16* gB = B1 + (size_t)bn * 256 * D_MODEL;

  const int c0 = tid;
  const int r0 = c0 >> 2;
  const int s0 = (c0 & 3) ^ ((r0 >> 1) & 3);
  const size_t goff0 = (size_t)r0 * D_MODEL + s0 * 8;
  const size_t goff1 = goff0 + (size_t)128 * D_MODEL;
  const int ldsOff0 = wid * 512;
  const int ldsOff1 = 4096 + wid * 512;

  #define STAGE(gsrc, lplane, kb) do { \
    __builtin_amdgcn_global_load_lds(GLOBAL_AS((gsrc) + goff0 + (kb)), LDS_AS((lplane) + ldsOff0), 16, 0, 0); \
    __builtin_amdgcn_global_load_lds(GLOBAL_AS((gsrc) + goff1 + (kb)), LDS_AS((lplane) + ldsOff1), 16, 0, 0); \
  } while (0)

  #define WAIT_VM8  asm volatile("s_waitcnt vmcnt(8)" ::: "memory")
  #define WAIT_LGKM asm volatile("s_waitcnt lgkmcnt(0)" ::: "memory")
  #define BAR()     __builtin_amdgcn_s_barrier()

  f32x4 acc[8][4] = {};
  half8 af[8], bf0, bf1;

  STAGE(gA, &As[0][0][0][0], 0);
  STAGE(gB, &Bs[0][0][0][0], 0);
  STAGE(gA, &As[0][1][0][0], 32);
  STAGE(gB, &Bs[0][1][0][0], 32);
  STAGE(gA, &As[1][0][0][0], 64);
  STAGE(gB, &Bs[1][0][0][0], 64);
  WAIT_VM8; BAR();

  #pragma unroll 1
  for (int t = 0; t < NT; ++t) {
    const int buf = t & 1, nbuf = buf ^ 1;
    const int kt1 = (t+1 < NT ? t+1 : NT-1) * 64;
    const int kt2 = (t+2 < NT ? t+2 : NT-1) * 64;
    const _Float16* Ap0 = &As[buf][0][0][0];
    const _Float16* Bp0 = &Bs[buf][0][0][0];
    const _Float16* Ap1 = &As[buf][1][0][0];
    const _Float16* Bp1 = &Bs[buf][1][0][0];

    #pragma unroll
    for (int mi = 0; mi < 8; ++mi)
      af[mi] = *reinterpret_cast<const half8*>(Ap0 + (wm*128 + mi*16 + r16)*32 + slot8);
    bf0 = *reinterpret_cast<const half8*>(Bp0 + (wn*64 +  0 + r16)*32 + slot8);
    bf1 = *reinterpret_cast<const half8*>(Bp0 + (wn*64 + 16 + r16)*32 + slot8);
    STAGE(gA, &As[nbuf][1][0][0], kt1 + 32);
    BAR(); WAIT_LGKM;
    __builtin_amdgcn_s_setprio(1);
    #pragma unroll
    for (int mi = 0; mi < 8; ++mi) {
      acc[mi][0] = __builtin_amdgcn_mfma_f32_16x16x32_f16(af[mi], bf0, acc[mi][0], 0, 0, 0);
      acc[mi][1] = __builtin_amdgcn_mfma_f32_16x16x32_f16(af[mi], bf1, acc[mi][1], 0, 0, 0);
    }
    __builtin_amdgcn_s_setprio(0);
    BAR();

    bf0 = *reinterpret_cast<const half8*>(Bp0 + (wn*64 + 32 + r16)*32 + slot8);
    bf1 = *reinterpret_cast<const half8*>(Bp0 + (wn*64 + 48 + r16)*32 + slot8);
    STAGE(gB, &Bs[nbuf][1][0][0], kt1 + 32);
    BAR(); WAIT_LGKM;
    __builtin_amdgcn_s_setprio(1);
    #pragma unroll
    for (int mi = 0; mi < 8; ++mi) {
      acc[mi][2] = __builtin_amdgcn_mfma_f32_16x16x32_f16(af[mi], bf0, acc[mi][2], 0, 0, 0);
      acc[mi][3] = __builtin_amdgcn_mfma_f32_16x16x32_f16(af[mi], bf1, acc[mi][3], 0, 0, 0);
    }
    __builtin_amdgcn_s_setprio(0);
    WAIT_VM8; BAR();

    #pragma unroll
    for (int mi = 0; mi < 8; ++mi)
      af[mi] = *reinterpret_cast<const half8*>(Ap1 + (wm*128 + mi*16 + r16)*32 + slot8);
    bf0 = *reinterpret_cast<const half8*>(Bp1 + (wn*64 +  0 + r16)*32 + slot8);
    bf1 = *reinterpret_cast<const half8*>(Bp1 + (wn*64 + 16 + r16)*32 + slot8);
    STAGE(gA, &As[buf][0][0][0], kt2);
    BAR(); WAIT_LGKM;
    __builtin_amdgcn_s_setprio(1);
    #pragma unroll
    for (int mi = 0; mi < 8; ++mi) {
      acc[mi][0] = __builtin_amdgcn_mfma_f32_16x16x32_f16(af[mi], bf0, acc[mi][0], 0, 0, 0);
      acc[mi][1] = __builtin_amdgcn_mfma_f32_16x16x32_f16(af[mi], bf1, acc[mi][1], 0, 0, 0);
    }
    __builtin_amdgcn_s_setprio(0);
    BAR();

    bf0 = *reinterpret_cast<const half8*>(Bp1 + (wn*64 + 32 + r16)*32 + slot8);
    bf1 = *reinterpret_cast<const half8*>(Bp1 + (wn*64 + 48 + r16)*32 + slot8);
    STAGE(gB, &Bs[buf][0][0][0], kt2);
    BAR(); WAIT_LGKM;
    __builtin_amdgcn_s_setprio(1);
    #pragma unroll
    for (int mi = 0; mi < 8; ++mi) {
      acc[mi][2] = __builtin_amdgcn_mfma_f32_16x16x32_f16(af[mi], bf0, acc[mi][2], 0, 0, 0);
      acc[mi][3] = __builtin_amdgcn_mfma_f32_16x16x32_f16(af[mi], bf1, acc[mi][3], 0, 0, 0);
    }
    __builtin_amdgcn_s_setprio(0);
    WAIT_VM8; BAR();
  }

  asm volatile("s_waitcnt vmcnt(0) lgkmcnt(0)" ::: "memory");

  // epilogue: C/D layout col=lane&15, row=(lane>>4)*4+reg [m89-verified]
  const int row0 = bm*256 + wm*128 + khalf*4;
  const int col0 = bn*256 + wn*64 + r16;
  if (fused) {
    // --- LDS-aggregated compaction: 1 global atomic per (row, block) ---
    __syncthreads();                                  // all LDS reads done; safe to reuse As/Bs
    int2* lbuf = (int2*)&As[0][0][0][0];              // 256 rows x LCAP entries = 48 KB
    int*  lcnt = (int*)&Bs[0][0][0][0];               // 256 ints
    for (int r = tid; r < 256; r += 512) lcnt[r] = 0;
    __syncthreads();

    const int lrow0 = wm*128 + khalf*4;
    #pragma unroll
    for (int ni = 0; ni < 4; ++ni) {
      const int col = col0 + ni*16;
      const float b = enc_bias[col];
      #pragma unroll
      for (int mi = 0; mi < 8; ++mi) {
        const int lrow = lrow0 + mi*16;
        #pragma unroll
        for (int r = 0; r < 4; ++r) {
          const float v = acc[mi][ni][r] * INV_SCALE + b;
          if (v > GUARD) {
            const int p = atomicAdd(&lcnt[lrow + r], 1);
            if (p < LCAP) lbuf[(lrow + r)*LCAP + p] = make_int2(col, __float_as_int(v));
            else {
              const int gp = atomicAdd(&counts[(bm*256 + lrow + r)*CNTSTR], 1);
              if (gp < RAWCAP) raw[(size_t)(bm*256 + lrow + r) * RAWCAP + gp] = make_int2(col, __float_as_int(v));
            }
          }
        }
      }
    }
    __syncthreads();

    if (tid < 256) {
      int lc = lcnt[tid]; if (lc > LCAP) lc = LCAP;
      if (lc > 0) {
        const int grow = bm*256 + tid;
        const int base = atomicAdd(&counts[grow*CNTSTR], lc);
        for (int i = 0; i < lc; ++i) {
          const int p = base + i;
          if (p < RAWCAP) raw[(size_t)grow * RAWCAP + p] = lbuf[tid*LCAP + i];
        }
      }
    }
  } else {
    #pragma unroll
    for (int ni = 0; ni < 4; ++ni) {
      const int col = col0 + ni*16;
      const float b = enc_bias[col];
      #pragma unroll
      for (int mi = 0; mi < 8; ++mi) {
        const int row = row0 + mi*16;
        #pragma unroll
        for (int r = 0; r < 4; ++r)
          C[(size_t)(row + r) * D_SPARSE + col] = acc[mi][ni][r] * INV_SCALE + b;
      }
    }
  }
  #undef STAGE
  #undef WAIT_VM8
  #undef WAIT_LGKM
  #undef BAR
}

// ---------- shared helpers ----------
__device__ __forceinline__ uint32_t f2key(float f) {
  uint32_t b = __float_as_uint(f);
  return (b & 0x80000000u) ? ~b : (b | 0x80000000u);
}
__device__ __forceinline__ float key2f(uint32_t k) {
  uint32_t b = (k & 0x80000000u) ? (k ^ 0x80000000u) : ~k;
  return __uint_as_float(b);
}
__device__ float preact_f32(int s, const float* __restrict__ hrow,
                            const float* __restrict__ pre_bias,
                            const float* __restrict__ W,
                            const float* __restrict__ enc_bias) {
  const float* wrow = W + (size_t)s * D_MODEL;
  float acc = 0.f;
  for (int k = 0; k < D_MODEL; ++k) acc += (hrow[k] - pre_bias[k]) * wrow[k];
  return acc + enc_bias[s];
}

// ---------- fused select: radix on compact raw list + fp64 rescue; GEMV fallback ----------
__global__ __launch_bounds__(256) void topk_select_fused(const int2* __restrict__ raw,
                                                         const int* __restrict__ counts,
                                                         const float* __restrict__ h,
                                                         const float* __restrict__ pre_bias,
                                                         const float* __restrict__ W,
                                                         const float* __restrict__ enc_bias,
                                                         int2* __restrict__ lists) {
  const int row = blockIdx.x;
  const int tid  = threadIdx.x;
  const int lane = tid & 63;
  const int wid  = tid >> 6;

  __shared__ float lv[RAWCAP];
  __shared__ int   li[RAWCAP];
  __shared__ int hist4[4][256];
  __shared__ int wsum[4];
  __shared__ int s_found, s_digit, s_rem, s_ucnt, s_emit;
  __shared__ int u_idx[MAXU];
  __shared__ double u_val[MAXU];
  __shared__ unsigned char u_sel[MAXU];

  const float* hrow = h + (size_t)row * D_MODEL;
  const int cntRaw = counts[row * CNTSTR];
  const int cnt = cntRaw < RAWCAP ? cntRaw : RAWCAP;
  bool mainok = (cntRaw >= K_SPARSE && cntRaw <= RAWCAP);
  float kth = 0.0f;

  if (mainok) {
    for (int e = tid; e < cnt; e += 256) {
      const int2 p = raw[(size_t)row * RAWCAP + e];
      li[e] = p.x; lv[e] = __int_as_float(p.y);
    }
    __syncthreads();
    uint32_t prefix = 0, pmask = 0;
    int remaining = K_SPARSE;
    for (int level = 0; level < 4; ++level) {
      const int shift = 24 - 8*level;
      #pragma unroll
      for (int w = 0; w < 4; ++w) hist4[w][tid] = 0;
      if (tid == 0) s_found = 1 << 30;
      __syncthreads();
      for (int e = tid; e < cnt; e += 256) {
        const uint32_t k = __float_as_uint(lv[e]);   // positive floats: raw bits monotone
        if ((k & pmask) == prefix) atomicAdd(&hist4[wid][(k >> shift) & 255], 1);
      }
      __syncthreads();
      const int bin = 255 - tid;
      const int cb = hist4[0][bin] + hist4[1][bin] + hist4[2][bin] + hist4[3][bin];
      int sc = cb;
      #pragma unroll
      for (int d = 1; d < 64; d <<= 1) {
        const int o = __shfl_up(sc, d, 64);
        if (lane >= d) sc += o;
      }
      if (lane == 63) wsum[wid] = sc;
      __syncthreads();
      int woff = 0;
      for (int w = 0; w < wid; ++w) woff += wsum[w];
      sc += woff;
      if (sc >= remaining) atomicMin(&s_found, tid);
      __syncthreads();
      if (tid == s_found) { s_digit = bin; s_rem = remaining - (sc - cb); }
      __syncthreads();
      prefix |= ((uint32_t)s_digit) << shift;
      pmask  |= 0xFFu << shift;
      remaining = s_rem;
      __syncthreads();
    }
    kth = __uint_as_float(prefix);
    if (!(kth - DELTA > GUARD)) mainok = false;   // window must stay inside list coverage
  }

  if (!mainok) {
    // exact fp32 on-the-fly radix (correctness escape; never taken on this data)
    uint32_t prefix = 0, pmask = 0;
    int remaining = K_SPARSE;
    for (int level = 0; level < 4; ++level) {
      const int shift = 24 - 8*level;
      #pragma unroll
      for (int w = 0; w < 4; ++w) hist4[w][tid] = 0;
      if (tid == 0) s_found = 1 << 30;
      __syncthreads();
      for (int j = 0; j < D_SPARSE/256; ++j) {
        const uint32_t k = f2key(preact_f32(tid + j*256, hrow, pre_bias, W, enc_bias));
        if ((k & pmask) == prefix) atomicAdd(&hist4[wid][(k >> shift) & 255], 1);
      }
      __syncthreads();
      const int bin = 255 - tid;
      const int cb = hist4[0][bin] + hist4[1][bin] + hist4[2][bin] + hist4[3][bin];
      int sc = cb;
      #pragma unroll
      for (int d = 1; d < 64; d <<= 1) {
        const int o = __shfl_up(sc, d, 64);
        if (lane >= d) sc += o;
      }
      if (lane == 63) wsum[wid] = sc;
      __syncthreads();
      int woff = 0;
      for (int w = 0; w < wid; ++w) woff += wsum[w];
      sc += woff;
      if (sc >= remaining) atomicMin(&s_found, tid);
      __syncthreads();
      if (tid == s_found) { s_digit = bin; s_rem = remaining - (sc - cb); }
      __syncthreads();
      prefix |= ((uint32_t)s_digit) << shift;
      pmask  |= 0xFFu << shift;
      remaining = s_rem;
      __syncthreads();
    }
    kth = key2f(prefix);
  }

  const float thrHi = kth + DELTA;
  const float thrLo = kth - DELTA;
  int2* __restrict__ rowlist = lists + (size_t)row * K_SPARSE;

  if (tid == 0) { s_ucnt = 0; s_emit = 0; }
  __syncthreads();

  if (mainok) {
    for (int e = tid; e < cnt; e += 256) {
      const float x = lv[e];
      if (x > thrHi) {
        const int p = atomicAdd(&s_emit, 1);
        if (p < K_SPARSE) rowlist[p] = make_int2(li[e], __float_as_int(fmaxf(x, 0.0f)));
      } else if (x >= thrLo) {
        const int p = atomicAdd(&s_ucnt, 1);
        if (p < MAXU) u_idx[p] = li[e];
      }
    }
  } else {
    for (int j = 0; j < D_SPARSE/256; ++j) {
      const int s = tid + j*256;
      const float x = preact_f32(s, hrow, pre_bias, W, enc_bias);
      if (x > thrHi) {
        const int p = atomicAdd(&s_emit, 1);
        if (p < K_SPARSE) rowlist[p] = make_int2(s, __float_as_int(fmaxf(x, 0.0f)));
      } else if (x >= thrLo) {
        const int p = atomicAdd(&s_ucnt, 1);
        if (p < MAXU) u_idx[p] = s;
      }
    }
  }
  __syncthreads();

  const int nabove = s_emit;
  const int ucnt = s_ucnt < MAXU ? s_ucnt : MAXU;
  int m = K_SPARSE - nabove;
  if (m < 0) m = 0; if (m > ucnt) m = ucnt;

  for (int e = wid; e < ucnt; e += 4) {
    const int ci = u_idx[e];
    const float* wrow = W + (size_t)ci * D_MODEL;
    double s = 0.0;
    for (int k = lane; k < D_MODEL; k += 64)
      s += (double)(hrow[k] - pre_bias[k]) * (double)wrow[k];
    #pragma unroll
    for (int off = 32; off; off >>= 1) s += __shfl_down(s, off, 64);
    if (lane == 0) u_val[e] = s + (double)enc_bias[ci];
  }
  __syncthreads();

  if (tid == 0) {
    for (int e = 0; e < ucnt; ++e) u_sel[e] = 0;
    for (int t = 0; t < m; ++t) {
      int best = -1;
      for (int e = 0; e < ucnt; ++e) {
        if (u_sel[e]) continue;
        if (best < 0 || u_val[e] > u_val[best] ||
            (u_val[e] == u_val[best] && u_idx[e] < u_idx[best])) best = e;
      }
      if (best >= 0) u_sel[best] = 1;
    }
  }
  __syncthreads();

  for (int e = tid; e < ucnt; e += 256)
    if (u_sel[e]) {
      const int p = atomicAdd(&s_emit, 1);
      if (p < K_SPARSE) rowlist[p] = make_int2(u_idx[e], __float_as_int(fmaxf((float)u_val[e], 0.0f)));
    }
  __syncthreads();
  if (tid == 0)
    for (int p = s_emit; p < K_SPARSE; ++p) rowlist[p] = make_int2(-1, 0);
}

// ---------- mem-path select (round-6 verified; used when ws too small) ----------
__global__ __launch_bounds__(256) void topk_select_mem(const float* __restrict__ C,
                                                       const float* __restrict__ h,
                                                       const float* __restrict__ pre_bias,
                                                       const float* __restrict__ W,
                                                       const float* __restrict__ enc_bias,
                                                       int2* __restrict__ lists) {
  const int row = blockIdx.x;
  const float* __restrict__ Crow = C + (size_t)row * D_SPARSE;
  const int tid  = threadIdx.x;
  const int lane = tid & 63;
  const int wid  = tid >> 6;

  __shared__ float lv[CAP];
  __shared__ int   li[CAP];
  __shared__ int hist4[4][256];
  __shared__ int wsum[4];
  __shared__ int s_cnt, s_found, s_digit, s_rem, s_ucnt, s_emit;
  __shared__ int u_idx[MAXU];
  __shared__ double u_val[MAXU];
  __shared__ unsigned char u_sel[MAXU];

  if (tid == 0) s_cnt = 0;
  __syncthreads();

  for (int j = 0; j < 24; ++j) {
    const float4 v = reinterpret_cast<const float4*>(Crow)[tid + j*256];
    const int base = (tid + j*256) * 4;
    #pragma unroll
    for (int c = 0; c < 4; ++c) {
      const float x = (&v.x)[c];
      if (x > GUARD) {
        const int p = atomicAdd(&s_cnt, 1);
        if (p < CAP) { lv[p] = x; li[p] = base + c; }
      }
    }
  }
  __syncthreads();
  const int cnt = s_cnt;
  bool mainok = (cnt >= K_SPARSE && cnt <= CAP);
  float kth = 0.0f;

  if (mainok) {
    uint32_t prefix = 0, pmask = 0;
    int remaining = K_SPARSE;
    for (int level = 0; level < 4; ++level) {
      const int shift = 24 - 8*level;
      #pragma unroll
      for (int w = 0; w < 4; ++w) hist4[w][tid] = 0;
      if (tid == 0) s_found = 1 << 30;
      __syncthreads();
      for (int e = tid; e < cnt; e += 256) {
        const uint32_t k = __float_as_uint(lv[e]);
        if ((k & pmask) == prefix) atomicAdd(&hist4[wid][(k >> shift) & 255], 1);
      }
      __syncthreads();
      const int bin = 255 - tid;
      const int cb = hist4[0][bin] + hist4[1][bin] + hist4[2][bin] + hist4[3][bin];
      int sc = cb;
      #pragma unroll
      for (int d = 1; d < 64; d <<= 1) {
        const int o = __shfl_up(sc, d, 64);
        if (lane >= d) sc += o;
      }
      if (lane == 63) wsum[wid] = sc;
      __syncthreads();
      int woff = 0;
      for (int w = 0; w < wid; ++w) woff += wsum[w];
      sc += woff;
      if (sc >= remaining) atomicMin(&s_found, tid);
      __syncthreads();
      if (tid == s_found) { s_digit = bin; s_rem = remaining - (sc - cb); }
      __syncthreads();
      prefix |= ((uint32_t)s_digit) << shift;
      pmask  |= 0xFFu << shift;
      remaining = s_rem;
      __syncthreads();
    }
    kth = __uint_as_float(prefix);
    if (!(kth - DELTA > GUARD)) mainok = false;
  }

  if (!mainok) {
    uint32_t prefix = 0, pmask = 0;
    int remaining = K_SPARSE;
    for (int level = 0; level < 4; ++level) {
      const int shift = 24 - 8*level;
      #pragma unroll
      for (int w = 0; w < 4; ++w) hist4[w][tid] = 0;
      if (tid == 0) s_found = 1 << 30;
      __syncthreads();
      for (int j = 0; j < 24; ++j) {
        const float4 v = reinterpret_cast<const float4*>(Crow)[tid + j*256];
        #pragma unroll
        for (int c = 0; c < 4; ++c) {
          const uint32_t k = f2key((&v.x)[c]);
          if ((k & pmask) == prefix) atomicAdd(&hist4[wid][(k >> shift) & 255], 1);
        }
      }
      __syncthreads();
      const int bin = 255 - tid;
      const int cb = hist4[0][bin] + hist4[1][bin] + hist4[2][bin] + hist4[3][bin];
      int sc = cb;
      #pragma unroll
      for (int d = 1; d < 64; d <<= 1) {
        const int o = __shfl_up(sc, d, 64);
        if (lane >= d) sc += o;
      }
      if (lane == 63) wsum[wid] = sc;
      __syncthreads();
      int woff = 0;
      for (int w = 0; w < wid; ++w) woff += wsum[w];
      sc += woff;
      if (sc >= remaining) atomicMin(&s_found, tid);
      __syncthreads();
      if (tid == s_found) { s_digit = bin; s_rem = remaining - (sc - cb); }
      __syncthreads();
      prefix |= ((uint32_t)s_digit) << shift;
      pmask  |= 0xFFu << shift;
      remaining = s_rem;
      __syncthreads();
    }
    kth = key2f(prefix);
  }

  const float thrHi = kth + DELTA;
  const float thrLo = kth - DELTA;
  int2* __restrict__ rowlist = lists + (size_t)row * K_SPARSE;

  if (tid == 0) { s_ucnt = 0; s_emit = 0; }
  __syncthreads();

  if (mainok) {
    for (int e = tid; e < cnt; e += 256) {
      const float x = lv[e];
      if (x > thrHi) {
        const int p = atomicAdd(&s_emit, 1);
        if (p < K_SPARSE) rowlist[p] = make_int2(li[e], __float_as_int(fmaxf(x, 0.0f)));
      } else if (x >= thrLo) {
        const int p = atomicAdd(&s_ucnt, 1);
        if (p < MAXU) u_idx[p] = li[e];
      }
    }
  } else {
    for (int j = 0; j < 24; ++j) {
      const float4 v = reinterpret_cast<const float4*>(Crow)[tid + j*256];
      const int base = (tid + j*256) * 4;
      #pragma unroll
      for (int c = 0; c < 4; ++c) {
        const float x = (&v.x)[c];
        if (x > thrHi) {
          const int p = atomicAdd(&s_emit, 1);
          if (p < K_SPARSE) rowlist[p] = make_int2(base + c, __float_as_int(fmaxf(x, 0.0f)));
        } else if (x >= thrLo) {
          const int p = atomicAdd(&s_ucnt, 1);
          if (p < MAXU) u_idx[p] = base + c;
        }
      }
    }
  }
  __syncthreads();

  const int nabove = s_emit;
  const int ucnt = s_ucnt < MAXU ? s_ucnt : MAXU;
  int m = K_SPARSE - nabove;
  if (m < 0) m = 0; if (m > ucnt) m = ucnt;

  const float* hrow = h + (size_t)row * D_MODEL;
  for (int e = wid; e < ucnt; e += 4) {
    const int ci = u_idx[e];
    const float* wrow = W + (size_t)ci * D_MODEL;
    double s = 0.0;
    for (int k = lane; k < D_MODEL; k += 64)
      s += (double)(hrow[k] - pre_bias[k]) * (double)wrow[k];
    #pragma unroll
    for (int off = 32; off; off >>= 1) s += __shfl_down(s, off, 64);
    if (lane == 0) u_val[e] = s + (double)enc_bias[ci];
  }
  __syncthreads();

  if (tid == 0) {
    for (int e = 0; e < ucnt; ++e) u_sel[e] = 0;
    for (int t = 0; t < m; ++t) {
      int best = -1;
      for (int e = 0; e < ucnt; ++e) {
        if (u_sel[e]) continue;
        if (best < 0 || u_val[e] > u_val[best] ||
            (u_val[e] == u_val[best] && u_idx[e] < u_idx[best])) best = e;
      }
      if (best >= 0) u_sel[best] = 1;
    }
  }
  __syncthreads();

  for (int e = tid; e < ucnt; e += 256)
    if (u_sel[e]) {
      const int p = atomicAdd(&s_emit, 1);
      if (p < K_SPARSE) rowlist[p] = make_int2(u_idx[e], __float_as_int(fmaxf((float)u_val[e], 0.0f)));
    }
  __syncthreads();
  if (tid == 0)
    for (int p = s_emit; p < K_SPARSE; ++p) rowlist[p] = make_int2(-1, 0);
}

// ---------- top-k write: zero + scatter via LDS span, pure streaming ----------
__global__ __launch_bounds__(256) void topk_write(const int2* __restrict__ lists,
                                                  float* __restrict__ C) {
  const int nseg = D_SPARSE / SEG;              // 6
  const int row = blockIdx.x / nseg;
  const int seg = blockIdx.x % nseg;
  const int lo  = seg * SEG;
  const int tid = threadIdx.x;

  __shared__ float span[SEG];
  const float4 z = {0.0f, 0.0f, 0.0f, 0.0f};
  #pragma unroll
  for (int i = 0; i < SEG/1024; ++i)
    reinterpret_cast<float4*>(span)[tid + i*256] = z;
  __syncthreads();

  if (tid < K_SPARSE) {
    const int2 p = lists[(size_t)row * K_SPARSE + tid];
    const int off = p.x - lo;
    if (off >= 0 && off < SEG) span[off] = __int_as_float(p.y);
  }
  __syncthreads();

  float4* __restrict__ out4 = reinterpret_cast<float4*>(C + (size_t)row * D_SPARSE + lo);
  #pragma unroll
  for (int i = 0; i < SEG/1024; ++i)
    out4[tid + i*256] = reinterpret_cast<const float4*>(span)[tid + i*256];
}

// ---------------------------------------------------------------------------
extern "C" void kernel_launch(void* const* d_in, const int* in_sizes, int n_in,
                              void* d_out, int out_size, void* d_ws, size_t ws_size,
                              hipStream_t stream) {
  const float* h        = (const float*)d_in[0];
  const float* W        = (const float*)d_in[1];
  const float* pre_bias = (const float*)d_in[2];
  const float* enc_bias = (const float*)d_in[3];
  float* C = (float*)d_out;

  const size_t a1_bytes  = (size_t)N_TOKENS * D_MODEL * sizeof(_Float16);   // 50.3 MB
  const size_t b1_bytes  = (size_t)D_SPARSE * D_MODEL * sizeof(_Float16);   // 151.0 MB
  const size_t raw_bytes = (size_t)N_TOKENS * RAWCAP * sizeof(int2);        // 50.3 MB
  const size_t cnt_bytes = (size_t)N_TOKENS * CNTSTR * sizeof(int);         // 512 KB
  const size_t fin_bytes = (size_t)N_TOKENS * K_SPARSE * sizeof(int2);      // 8 MB
  if (ws_size < a1_bytes + b1_bytes) return;

  char* base = (char*)d_ws;
  _Float16* A1 = (_Float16*)base;
  _Float16* B1 = (_Float16*)(base + a1_bytes);

  const bool fused = ws_size >= a1_bytes + b1_bytes + raw_bytes + cnt_bytes + fin_bytes;
  int2* raw    = (int2*)(base + a1_bytes + b1_bytes);
  int*  counts = (int*)(base + a1_bytes + b1_bytes + raw_bytes);
  int2* fin    = fused ? (int2*)(base + a1_bytes + b1_bytes + raw_bytes + cnt_bytes)
                       : (int2*)base;   // mem path: A1 region is dead post-GEMM

  convert_h_kernel<<<2048, 256, 0, stream>>>(h, pre_bias, A1);
  convert_w_kernel<<<4096, 256, 0, stream>>>(W, B1);
  if (fused) zero_counts_kernel<<<(N_TOKENS*CNTSTR + 255)/256, 256, 0, stream>>>(counts);
  gemm_kernel<<<(N_TOKENS/256) * (D_SPARSE/256), 512, 0, stream>>>(
      A1, B1, enc_bias, C, raw, counts, fused ? 1 : 0);
  if (fused)
    topk_select_fused<<<N_TOKENS, 256, 0, stream>>>(raw, counts, h, pre_bias, W, enc_bias, fin);
  else
    topk_select_mem<<<N_TOKENS, 256, 0, stream>>>(C, h, pre_bias, W, enc_bias, fin);
  topk_write<<<N_TOKENS * (D_SPARSE/SEG), 256, 0, stream>>>(fin, C);
}

// Round 13
// 1878.651 us; speedup vs baseline: 1.0687x; 1.0164x over previous
//
#include <hip/hip_runtime.h>
#include <cstdint>
#include <cstddef>

#define D_MODEL   3072
#define D_SPARSE  24576
#define N_TOKENS  8192
#define K_SPARSE  128
#define NT        (D_MODEL/64)   // 48 K-tiles of BK=64

typedef _Float16 half8  __attribute__((ext_vector_type(8)));
typedef _Float16 half4v __attribute__((ext_vector_type(4)));
typedef float    f32x4  __attribute__((ext_vector_type(4)));

#define SCALE_A   64.0f
#define SCALE_B   4096.0f
#define INV_SCALE (1.0f/(SCALE_A*SCALE_B))   // 2^-18, exact

#define DELTA  6.0e-3f
#define MAXU   256
#define CAP    1536     // mem-path compact capacity
#define RAWCAP 768      // fused-path raw list capacity (mean ~560, +9 sigma)
#define GUARD  2.0f     // prefilter threshold; 128th value ~2.56
#define SEG    4096     // mem-path topk_write span per block
#define CNTSTR 16       // counts stride in ints (64B -> one row per cache line)
#define LCAP   24       // per-block per-row LDS list cap (mean 5.9, +7.4 sigma)

#define GLOBAL_AS(p) ((const __attribute__((address_space(1))) uint32_t*)(p))
#define LDS_AS(p)    ((__attribute__((address_space(3))) uint32_t*)(p))

// ---------- converts: fp32 -> fp16 (single hi limb), scaled ----------
__global__ void convert_h_kernel(const float* __restrict__ h,
                                 const float* __restrict__ pre_bias,
                                 _Float16* __restrict__ A1) {
  const int total4 = N_TOKENS * (D_MODEL/4);
  for (int m = blockIdx.x*blockDim.x + threadIdx.x; m < total4; m += gridDim.x*blockDim.x) {
    const int c4 = m % (D_MODEL/4);
    const float4 v  = reinterpret_cast<const float4*>(h)[m];
    const float4 pb = reinterpret_cast<const float4*>(pre_bias)[c4];
    half4v o;
    o[0] = (_Float16)((v.x-pb.x)*SCALE_A); o[1] = (_Float16)((v.y-pb.y)*SCALE_A);
    o[2] = (_Float16)((v.z-pb.z)*SCALE_A); o[3] = (_Float16)((v.w-pb.w)*SCALE_A);
    reinterpret_cast<half4v*>(A1)[m] = o;
  }
}

__global__ void convert_w_kernel(const float* __restrict__ W,
                                 _Float16* __restrict__ B1) {
  const int total4 = D_SPARSE * (D_MODEL/4);
  for (int m = blockIdx.x*blockDim.x + threadIdx.x; m < total4; m += gridDim.x*blockDim.x) {
    const float4 v = reinterpret_cast<const float4*>(W)[m];
    half4v o;
    o[0] = (_Float16)(v.x*SCALE_B); o[1] = (_Float16)(v.y*SCALE_B);
    o[2] = (_Float16)(v.z*SCALE_B); o[3] = (_Float16)(v.w*SCALE_B);
    reinterpret_cast<half4v*>(B1)[m] = o;
  }
}

__global__ void zero_counts_kernel(int* __restrict__ counts) {
  const int i = blockIdx.x * blockDim.x + threadIdx.x;
  if (i < N_TOKENS * CNTSTR) counts[i] = 0;
}

// ---------- 256x256 8-phase GEMM (round-9 verified schedule; best measured) ----------
__global__ __launch_bounds__(512) void gemm_kernel(const _Float16* __restrict__ A1,
                                                   const _Float16* __restrict__ B1,
                                                   const float* __restrict__ enc_bias,
                                                   float* __restrict__ C,
                                                   int2* __restrict__ raw,
                                                   int* __restrict__ counts,
                                                   int fused) {
  __shared__ _Float16 As[2][2][256][32];   // 64 KiB (reused as epilogue scratch)
  __shared__ _Float16 Bs[2][2][256][32];   // 64 KiB

  const int nwg = (N_TOKENS/256) * (D_SPARSE/256);      // 3072
  const int cpx = nwg / 8;
  const int swz = (blockIdx.x & 7) * cpx + (blockIdx.x >> 3);
  const int bm = swz / (D_SPARSE/256);
  const int bn = swz % (D_SPARSE/256);

  const int tid  = threadIdx.x;
  const int lane = tid & 63;
  const int wid  = tid >> 6;
  const int wm = wid >> 2;
  const int wn = wid & 3;

  const int r16   = lane & 15;
  const int khalf = lane >> 4;
  const int slot8 = ((khalf ^ ((r16 >> 1) & 3)) << 3);   // p(r)=(r>>1)&3 (conflict-free, r6-verified)

  const _Float16* gA = A1 + (size_t)bm * 256 * D_MODEL;
  const _Float16* gB = B1 + (size_t)bn * 256 * D_MODEL;

  const int c0 = tid;
  const int r0 = c0 >> 2;
  const int s0 = (c0 & 3) ^ ((r0 >> 1) & 3);
  const size_t goff0 = (size_t)r0 * D_MODEL + s0 * 8;
  const size_t goff1 = goff0 + (size_t)128 * D_MODEL;
  const int ldsOff0 = wid * 512;
  const int ldsOff1 = 4096 + wid * 512;

  #define STAGE(gsrc, lplane, kb) do { \
    __builtin_amdgcn_global_load_lds(GLOBAL_AS((gsrc) + goff0 + (kb)), LDS_AS((lplane) + ldsOff0), 16, 0, 0); \
    __builtin_amdgcn_global_load_lds(GLOBAL_AS((gsrc) + goff1 + (kb)), LDS_AS((lplane) + ldsOff1), 16, 0, 0); \
  } while (0)

  #define WAIT_VM8  asm volatile("s_waitcnt vmcnt(8)" ::: "memory")
  #define WAIT_LGKM asm volatile("s_waitcnt lgkmcnt(0)" ::: "memory")
  #define BAR()     __builtin_amdgcn_s_barrier()

  f32x4 acc[8][4] = {};
  half8 af[8], bf0, bf1;

  STAGE(gA, &As[0][0][0][0], 0);
  STAGE(gB, &Bs[0][0][0][0], 0);
  STAGE(gA, &As[0][1][0][0], 32);
  STAGE(gB, &Bs[0][1][0][0], 32);
  STAGE(gA, &As[1][0][0][0], 64);
  STAGE(gB, &Bs[1][0][0][0], 64);
  WAIT_VM8; BAR();

  #pragma unroll 1
  for (int t = 0; t < NT; ++t) {
    const int buf = t & 1, nbuf = buf ^ 1;
    const int kt1 = (t+1 < NT ? t+1 : NT-1) * 64;
    const int kt2 = (t+2 < NT ? t+2 : NT-1) * 64;
    const _Float16* Ap0 = &As[buf][0][0][0];
    const _Float16* Bp0 = &Bs[buf][0][0][0];
    const _Float16* Ap1 = &As[buf][1][0][0];
    const _Float16* Bp1 = &Bs[buf][1][0][0];

    #pragma unroll
    for (int mi = 0; mi < 8; ++mi)
      af[mi] = *reinterpret_cast<const half8*>(Ap0 + (wm*128 + mi*16 + r16)*32 + slot8);
    bf0 = *reinterpret_cast<const half8*>(Bp0 + (wn*64 +  0 + r16)*32 + slot8);
    bf1 = *reinterpret_cast<const half8*>(Bp0 + (wn*64 + 16 + r16)*32 + slot8);
    STAGE(gA, &As[nbuf][1][0][0], kt1 + 32);
    BAR(); WAIT_LGKM;
    __builtin_amdgcn_s_setprio(1);
    #pragma unroll
    for (int mi = 0; mi < 8; ++mi) {
      acc[mi][0] = __builtin_amdgcn_mfma_f32_16x16x32_f16(af[mi], bf0, acc[mi][0], 0, 0, 0);
      acc[mi][1] = __builtin_amdgcn_mfma_f32_16x16x32_f16(af[mi], bf1, acc[mi][1], 0, 0, 0);
    }
    __builtin_amdgcn_s_setprio(0);
    BAR();

    bf0 = *reinterpret_cast<const half8*>(Bp0 + (wn*64 + 32 + r16)*32 + slot8);
    bf1 = *reinterpret_cast<const half8*>(Bp0 + (wn*64 + 48 + r16)*32 + slot8);
    STAGE(gB, &Bs[nbuf][1][0][0], kt1 + 32);
    BAR(); WAIT_LGKM;
    __builtin_amdgcn_s_setprio(1);
    #pragma unroll
    for (int mi = 0; mi < 8; ++mi) {
      acc[mi][2] = __builtin_amdgcn_mfma_f32_16x16x32_f16(af[mi], bf0, acc[mi][2], 0, 0, 0);
      acc[mi][3] = __builtin_amdgcn_mfma_f32_16x16x32_f16(af[mi], bf1, acc[mi][3], 0, 0, 0);
    }
    __builtin_amdgcn_s_setprio(0);
    WAIT_VM8; BAR();

    #pragma unroll
    for (int mi = 0; mi < 8; ++mi)
      af[mi] = *reinterpret_cast<const half8*>(Ap1 + (wm*128 + mi*16 + r16)*32 + slot8);
    bf0 = *reinterpret_cast<const half8*>(Bp1 + (wn*64 +  0 + r16)*32 + slot8);
    bf1 = *reinterpret_cast<const half8*>(Bp1 + (wn*64 + 16 + r16)*32 + slot8);
    STAGE(gA, &As[buf][0][0][0], kt2);
    BAR(); WAIT_LGKM;
    __builtin_amdgcn_s_setprio(1);
    #pragma unroll
    for (int mi = 0; mi < 8; ++mi) {
      acc[mi][0] = __builtin_amdgcn_mfma_f32_16x16x32_f16(af[mi], bf0, acc[mi][0], 0, 0, 0);
      acc[mi][1] = __builtin_amdgcn_mfma_f32_16x16x32_f16(af[mi], bf1, acc[mi][1], 0, 0, 0);
    }
    __builtin_amdgcn_s_setprio(0);
    BAR();

    bf0 = *reinterpret_cast<const half8*>(Bp1 + (wn*64 + 32 + r16)*32 + slot8);
    bf1 = *reinterpret_cast<const half8*>(Bp1 + (wn*64 + 48 + r16)*32 + slot8);
    STAGE(gB, &Bs[buf][0][0][0], kt2);
    BAR(); WAIT_LGKM;
    __builtin_amdgcn_s_setprio(1);
    #pragma unroll
    for (int mi = 0; mi < 8; ++mi) {
      acc[mi][2] = __builtin_amdgcn_mfma_f32_16x16x32_f16(af[mi], bf0, acc[mi][2], 0, 0, 0);
      acc[mi][3] = __builtin_amdgcn_mfma_f32_16x16x32_f16(af[mi], bf1, acc[mi][3], 0, 0, 0);
    }
    __builtin_amdgcn_s_setprio(0);
    WAIT_VM8; BAR();
  }

  asm volatile("s_waitcnt vmcnt(0) lgkmcnt(0)" ::: "memory");

  // epilogue: C/D layout col=lane&15, row=(lane>>4)*4+reg [m89-verified]
  const int row0 = bm*256 + wm*128 + khalf*4;
  const int col0 = bn*256 + wn*64 + r16;
  if (fused) {
    // --- LDS-aggregated compaction: 1 global atomic per (row, block) ---
    __syncthreads();                                  // all LDS reads done; safe to reuse As/Bs
    int2* lbuf = (int2*)&As[0][0][0][0];              // 256 rows x LCAP entries = 48 KB
    int*  lcnt = (int*)&Bs[0][0][0][0];               // 256 ints
    for (int r = tid; r < 256; r += 512) lcnt[r] = 0;
    __syncthreads();

    const int lrow0 = wm*128 + khalf*4;
    #pragma unroll
    for (int ni = 0; ni < 4; ++ni) {
      const int col = col0 + ni*16;
      const float b = enc_bias[col];
      #pragma unroll
      for (int mi = 0; mi < 8; ++mi) {
        const int lrow = lrow0 + mi*16;
        #pragma unroll
        for (int r = 0; r < 4; ++r) {
          const float v = acc[mi][ni][r] * INV_SCALE + b;
          if (v > GUARD) {
            const int p = atomicAdd(&lcnt[lrow + r], 1);
            if (p < LCAP) lbuf[(lrow + r)*LCAP + p] = make_int2(col, __float_as_int(v));
            else {
              const int gp = atomicAdd(&counts[(bm*256 + lrow + r)*CNTSTR], 1);
              if (gp < RAWCAP) raw[(size_t)(bm*256 + lrow + r) * RAWCAP + gp] = make_int2(col, __float_as_int(v));
            }
          }
        }
      }
    }
    __syncthreads();

    if (tid < 256) {
      int lc = lcnt[tid]; if (lc > LCAP) lc = LCAP;
      if (lc > 0) {
        const int grow = bm*256 + tid;
        const int base = atomicAdd(&counts[grow*CNTSTR], lc);
        for (int i = 0; i < lc; ++i) {
          const int p = base + i;
          if (p < RAWCAP) raw[(size_t)grow * RAWCAP + p] = lbuf[tid*LCAP + i];
        }
      }
    }
  } else {
    #pragma unroll
    for (int ni = 0; ni < 4; ++ni) {
      const int col = col0 + ni*16;
      const float b = enc_bias[col];
      #pragma unroll
      for (int mi = 0; mi < 8; ++mi) {
        const int row = row0 + mi*16;
        #pragma unroll
        for (int r = 0; r < 4; ++r)
          C[(size_t)(row + r) * D_SPARSE + col] = acc[mi][ni][r] * INV_SCALE + b;
      }
    }
  }
  #undef STAGE
  #undef WAIT_VM8
  #undef WAIT_LGKM
  #undef BAR
}

// ---------- shared helpers ----------
__device__ __forceinline__ uint32_t f2key(float f) {
  uint32_t b = __float_as_uint(f);
  return (b & 0x80000000u) ? ~b : (b | 0x80000000u);
}
__device__ __forceinline__ float key2f(uint32_t k) {
  uint32_t b = (k & 0x80000000u) ? (k ^ 0x80000000u) : ~k;
  return __uint_as_float(b);
}
__device__ float preact_f32(int s, const float* __restrict__ hrow,
                            const float* __restrict__ pre_bias,
                            const float* __restrict__ W,
                            const float* __restrict__ enc_bias) {
  const float* wrow = W + (size_t)s * D_MODEL;
  float acc = 0.f;
  for (int k = 0; k < D_MODEL; ++k) acc += (hrow[k] - pre_bias[k]) * wrow[k];
  return acc + enc_bias[s];
}

// ---------- fused select+write: radix on raw list + fp64 rescue, then zero row + scatter ----------
__global__ __launch_bounds__(256) void topk_select_fused(const int2* __restrict__ raw,
                                                         const int* __restrict__ counts,
                                                         const float* __restrict__ h,
                                                         const float* __restrict__ pre_bias,
                                                         const float* __restrict__ W,
                                                         const float* __restrict__ enc_bias,
                                                         float* __restrict__ C) {
  const int row = blockIdx.x;
  const int tid  = threadIdx.x;
  const int lane = tid & 63;
  const int wid  = tid >> 6;

  __shared__ float lv[RAWCAP];
  __shared__ int   li[RAWCAP];
  __shared__ int hist4[4][256];
  __shared__ int wsum[4];
  __shared__ int s_found, s_digit, s_rem, s_ucnt, s_emit;
  __shared__ int u_idx[MAXU];
  __shared__ double u_val[MAXU];
  __shared__ unsigned char u_sel[MAXU];
  __shared__ int   keep_idx[K_SPARSE];
  __shared__ float keep_val[K_SPARSE];

  const float* hrow = h + (size_t)row * D_MODEL;
  const int cntRaw = counts[row * CNTSTR];
  const int cnt = cntRaw < RAWCAP ? cntRaw : RAWCAP;
  bool mainok = (cntRaw >= K_SPARSE && cntRaw <= RAWCAP);
  float kth = 0.0f;

  if (mainok) {
    for (int e = tid; e < cnt; e += 256) {
      const int2 p = raw[(size_t)row * RAWCAP + e];
      li[e] = p.x; lv[e] = __int_as_float(p.y);
    }
    __syncthreads();
    uint32_t prefix = 0, pmask = 0;
    int remaining = K_SPARSE;
    for (int level = 0; level < 4; ++level) {
      const int shift = 24 - 8*level;
      #pragma unroll
      for (int w = 0; w < 4; ++w) hist4[w][tid] = 0;
      if (tid == 0) s_found = 1 << 30;
      __syncthreads();
      for (int e = tid; e < cnt; e += 256) {
        const uint32_t k = __float_as_uint(lv[e]);   // positive floats: raw bits monotone
        if ((k & pmask) == prefix) atomicAdd(&hist4[wid][(k >> shift) & 255], 1);
      }
      __syncthreads();
      const int bin = 255 - tid;
      const int cb = hist4[0][bin] + hist4[1][bin] + hist4[2][bin] + hist4[3][bin];
      int sc = cb;
      #pragma unroll
      for (int d = 1; d < 64; d <<= 1) {
        const int o = __shfl_up(sc, d, 64);
        if (lane >= d) sc += o;
      }
      if (lane == 63) wsum[wid] = sc;
      __syncthreads();
      int woff = 0;
      for (int w = 0; w < wid; ++w) woff += wsum[w];
      sc += woff;
      if (sc >= remaining) atomicMin(&s_found, tid);
      __syncthreads();
      if (tid == s_found) { s_digit = bin; s_rem = remaining - (sc - cb); }
      __syncthreads();
      prefix |= ((uint32_t)s_digit) << shift;
      pmask  |= 0xFFu << shift;
      remaining = s_rem;
      __syncthreads();
    }
    kth = __uint_as_float(prefix);
    if (!(kth - DELTA > GUARD)) mainok = false;   // window must stay inside list coverage
  }

  if (!mainok) {
    // exact fp32 on-the-fly radix (correctness escape; never taken on this data)
    uint32_t prefix = 0, pmask = 0;
    int remaining = K_SPARSE;
    for (int level = 0; level < 4; ++level) {
      const int shift = 24 - 8*level;
      #pragma unroll
      for (int w = 0; w < 4; ++w) hist4[w][tid] = 0;
      if (tid == 0) s_found = 1 << 30;
      __syncthreads();
      for (int j = 0; j < D_SPARSE/256; ++j) {
        const uint32_t k = f2key(preact_f32(tid + j*256, hrow, pre_bias, W, enc_bias));
        if ((k & pmask) == prefix) atomicAdd(&hist4[wid][(k >> shift) & 255], 1);
      }
      __syncthreads();
      const int bin = 255 - tid;
      const int cb = hist4[0][bin] + hist4[1][bin] + hist4[2][bin] + hist4[3][bin];
      int sc = cb;
      #pragma unroll
      for (int d = 1; d < 64; d <<= 1) {
        const int o = __shfl_up(sc, d, 64);
        if (lane >= d) sc += o;
      }
      if (lane == 63) wsum[wid] = sc;
      __syncthreads();
      int woff = 0;
      for (int w = 0; w < wid; ++w) woff += wsum[w];
      sc += woff;
      if (sc >= remaining) atomicMin(&s_found, tid);
      __syncthreads();
      if (tid == s_found) { s_digit = bin; s_rem = remaining - (sc - cb); }
      __syncthreads();
      prefix |= ((uint32_t)s_digit) << shift;
      pmask  |= 0xFFu << shift;
      remaining = s_rem;
      __syncthreads();
    }
    kth = key2f(prefix);
  }

  const float thrHi = kth + DELTA;
  const float thrLo = kth - DELTA;

  if (tid == 0) { s_ucnt = 0; s_emit = 0; }
  __syncthreads();

  // ---- classify: sure-keeps -> LDS keep list; window candidates -> u_idx ----
  if (mainok) {
    for (int e = tid; e < cnt; e += 256) {
      const float x = lv[e];
      if (x > thrHi) {
        const int p = atomicAdd(&s_emit, 1);
        if (p < K_SPARSE) { keep_idx[p] = li[e]; keep_val[p] = fmaxf(x, 0.0f); }
      } else if (x >= thrLo) {
        const int p = atomicAdd(&s_ucnt, 1);
        if (p < MAXU) u_idx[p] = li[e];
      }
    }
  } else {
    for (int j = 0; j < D_SPARSE/256; ++j) {
      const int s = tid + j*256;
      const float x = preact_f32(s, hrow, pre_bias, W, enc_bias);
      if (x > thrHi) {
        const int p = atomicAdd(&s_emit, 1);
        if (p < K_SPARSE) { keep_idx[p] = s; keep_val[p] = fmaxf(x, 0.0f); }
      } else if (x >= thrLo) {
        const int p = atomicAdd(&s_ucnt, 1);
        if (p < MAXU) u_idx[p] = s;
      }
    }
  }
  __syncthreads();

  const int nabove = s_emit;
  const int ucnt = s_ucnt < MAXU ? s_ucnt : MAXU;
  int m = K_SPARSE - nabove;
  if (m < 0) m = 0; if (m > ucnt) m = ucnt;

  // ---- exact fp64 dots for window candidates, one wave each ----
  for (int e = wid; e < ucnt; e += 4) {
    const int ci = u_idx[e];
    const float* wrow = W + (size_t)ci * D_MODEL;
    double s = 0.0;
    for (int k = lane; k < D_MODEL; k += 64)
      s += (double)(hrow[k] - pre_bias[k]) * (double)wrow[k];
    #pragma unroll
    for (int off = 32; off; off >>= 1) s += __shfl_down(s, off, 64);
    if (lane == 0) u_val[e] = s + (double)enc_bias[ci];
  }
  __syncthreads();

  // ---- pick top-m by (exact desc, index asc) — jax tiebreak ----
  if (tid == 0) {
    for (int e = 0; e < ucnt; ++e) u_sel[e] = 0;
    for (int t = 0; t < m; ++t) {
      int best = -1;
      for (int e = 0; e < ucnt; ++e) {
        if (u_sel[e]) continue;
        if (best < 0 || u_val[e] > u_val[best] ||
            (u_val[e] == u_val[best] && u_idx[e] < u_idx[best])) best = e;
      }
      if (best >= 0) u_sel[best] = 1;
    }
  }
  __syncthreads();

  for (int e = tid; e < ucnt; e += 256)
    if (u_sel[e]) {
      const int p = atomicAdd(&s_emit, 1);
      if (p < K_SPARSE) { keep_idx[p] = u_idx[e]; keep_val[p] = fmaxf((float)u_val[e], 0.0f); }
    }
  __syncthreads();
  const int nkeep = s_emit < K_SPARSE ? s_emit : K_SPARSE;

  // ---- write phase: zero the row, drain, scatter the keep list ----
  {
    float* __restrict__ Crow = C + (size_t)row * D_SPARSE;
    const float4 z = {0.0f, 0.0f, 0.0f, 0.0f};
    float4* __restrict__ out4 = reinterpret_cast<float4*>(Crow);
    #pragma unroll
    for (int j = 0; j < D_SPARSE/1024; ++j)      // 24 float4 per thread
      out4[tid + j*256] = z;
    __syncthreads();                              // drains vmcnt(0): zeros committed
    for (int e = tid; e < nkeep; e += 256)
      Crow[keep_idx[e]] = keep_val[e];
  }
}

// ---------- mem-path select (round-6 verified; used when ws too small) ----------
__global__ __launch_bounds__(256) void topk_select_mem(const float* __restrict__ C,
                                                       const float* __restrict__ h,
                                                       const float* __restrict__ pre_bias,
                                                       const float* __restrict__ W,
                                                       const float* __restrict__ enc_bias,
                                                       int2* __restrict__ lists) {
  const int row = blockIdx.x;
  const float* __restrict__ Crow = C + (size_t)row * D_SPARSE;
  const int tid  = threadIdx.x;
  const int lane = tid & 63;
  const int wid  = tid >> 6;

  __shared__ float lv[CAP];
  __shared__ int   li[CAP];
  __shared__ int hist4[4][256];
  __shared__ int wsum[4];
  __shared__ int s_cnt, s_found, s_digit, s_rem, s_ucnt, s_emit;
  __shared__ int u_idx[MAXU];
  __shared__ double u_val[MAXU];
  __shared__ unsigned char u_sel[MAXU];

  if (tid == 0) s_cnt = 0;
  __syncthreads();

  for (int j = 0; j < 24; ++j) {
    const float4 v = reinterpret_cast<const float4*>(Crow)[tid + j*256];
    const int base = (tid + j*256) * 4;
    #pragma unroll
    for (int c = 0; c < 4; ++c) {
      const float x = (&v.x)[c];
      if (x > GUARD) {
        const int p = atomicAdd(&s_cnt, 1);
        if (p < CAP) { lv[p] = x; li[p] = base + c; }
      }
    }
  }
  __syncthreads();
  const int cnt = s_cnt;
  bool mainok = (cnt >= K_SPARSE && cnt <= CAP);
  float kth = 0.0f;

  if (mainok) {
    uint32_t prefix = 0, pmask = 0;
    int remaining = K_SPARSE;
    for (int level = 0; level < 4; ++level) {
      const int shift = 24 - 8*level;
      #pragma unroll
      for (int w = 0; w < 4; ++w) hist4[w][tid] = 0;
      if (tid == 0) s_found = 1 << 30;
      __syncthreads();
      for (int e = tid; e < cnt; e += 256) {
        const uint32_t k = __float_as_uint(lv[e]);
        if ((k & pmask) == prefix) atomicAdd(&hist4[wid][(k >> shift) & 255], 1);
      }
      __syncthreads();
      const int bin = 255 - tid;
      const int cb = hist4[0][bin] + hist4[1][bin] + hist4[2][bin] + hist4[3][bin];
      int sc = cb;
      #pragma unroll
      for (int d = 1; d < 64; d <<= 1) {
        const int o = __shfl_up(sc, d, 64);
        if (lane >= d) sc += o;
      }
      if (lane == 63) wsum[wid] = sc;
      __syncthreads();
      int woff = 0;
      for (int w = 0; w < wid; ++w) woff += wsum[w];
      sc += woff;
      if (sc >= remaining) atomicMin(&s_found, tid);
      __syncthreads();
      if (tid == s_found) { s_digit = bin; s_rem = remaining - (sc - cb); }
      __syncthreads();
      prefix |= ((uint32_t)s_digit) << shift;
      pmask  |= 0xFFu << shift;
      remaining = s_rem;
      __syncthreads();
    }
    kth = __uint_as_float(prefix);
    if (!(kth - DELTA > GUARD)) mainok = false;
  }

  if (!mainok) {
    uint32_t prefix = 0, pmask = 0;
    int remaining = K_SPARSE;
    for (int level = 0; level < 4; ++level) {
      const int shift = 24 - 8*level;
      #pragma unroll
      for (int w = 0; w < 4; ++w) hist4[w][tid] = 0;
      if (tid == 0) s_found = 1 << 30;
      __syncthreads();
      for (int j = 0; j < 24; ++j) {
        const float4 v = reinterpret_cast<const float4*>(Crow)[tid + j*256];
        #pragma unroll
        for (int c = 0; c < 4; ++c) {
          const uint32_t k = f2key((&v.x)[c]);
          if ((k & pmask) == prefix) atomicAdd(&hist4[wid][(k >> shift) & 255], 1);
        }
      }
      __syncthreads();
      const int bin = 255 - tid;
      const int cb = hist4[0][bin] + hist4[1][bin] + hist4[2][bin] + hist4[3][bin];
      int sc = cb;
      #pragma unroll
      for (int d = 1; d < 64; d <<= 1) {
        const int o = __shfl_up(sc, d, 64);
        if (lane >= d) sc += o;
      }
      if (lane == 63) wsum[wid] = sc;
      __syncthreads();
      int woff = 0;
      for (int w = 0; w < wid; ++w) woff += wsum[w];
      sc += woff;
      if (sc >= remaining) atomicMin(&s_found, tid);
      __syncthreads();
      if (tid == s_found) { s_digit = bin; s_rem = remaining - (sc - cb); }
      __syncthreads();
      prefix |= ((uint32_t)s_digit) << shift;
      pmask  |= 0xFFu << shift;
      remaining = s_rem;
      __syncthreads();
    }
    kth = key2f(prefix);
  }

  const float thrHi = kth + DELTA;
  const float thrLo = kth - DELTA;
  int2* __restrict__ rowlist = lists + (size_t)row * K_SPARSE;

  if (tid == 0) { s_ucnt = 0; s_emit = 0; }
  __syncthreads();

  if (mainok) {
    for (int e = tid; e < cnt; e += 256) {
      const float x = lv[e];
      if (x > thrHi) {
        const int p = atomicAdd(&s_emit, 1);
        if (p < K_SPARSE) rowlist[p] = make_int2(li[e], __float_as_int(fmaxf(x, 0.0f)));
      } else if (x >= thrLo) {
        const int p = atomicAdd(&s_ucnt, 1);
        if (p < MAXU) u_idx[p] = li[e];
      }
    }
  } else {
    for (int j = 0; j < 24; ++j) {
      const float4 v = reinterpret_cast<const float4*>(Crow)[tid + j*256];
      const int base = (tid + j*256) * 4;
      #pragma unroll
      for (int c = 0; c < 4; ++c) {
        const float x = (&v.x)[c];
        if (x > thrHi) {
          const int p = atomicAdd(&s_emit, 1);
          if (p < K_SPARSE) rowlist[p] = make_int2(base + c, __float_as_int(fmaxf(x, 0.0f)));
        } else if (x >= thrLo) {
          const int p = atomicAdd(&s_ucnt, 1);
          if (p < MAXU) u_idx[p] = base + c;
        }
      }
    }
  }
  __syncthreads();

  const int nabove = s_emit;
  const int ucnt = s_ucnt < MAXU ? s_ucnt : MAXU;
  int m = K_SPARSE - nabove;
  if (m < 0) m = 0; if (m > ucnt) m = ucnt;

  const float* hrow = h + (size_t)row * D_MODEL;
  for (int e = wid; e < ucnt; e += 4) {
    const int ci = u_idx[e];
    const float* wrow = W + (size_t)ci * D_MODEL;
    double s = 0.0;
    for (int k = lane; k < D_MODEL; k += 64)
      s += (double)(hrow[k] - pre_bias[k]) * (double)wrow[k];
    #pragma unroll
    for (int off = 32; off; off >>= 1) s += __shfl_down(s, off, 64);
    if (lane == 0) u_val[e] = s + (double)enc_bias[ci];
  }
  __syncthreads();

  if (tid == 0) {
    for (int e = 0; e < ucnt; ++e) u_sel[e] = 0;
    for (int t = 0; t < m; ++t) {
      int best = -1;
      for (int e = 0; e < ucnt; ++e) {
        if (u_sel[e]) continue;
        if (best < 0 || u_val[e] > u_val[best] ||
            (u_val[e] == u_val[best] && u_idx[e] < u_idx[best])) best = e;
      }
      if (best >= 0) u_sel[best] = 1;
    }
  }
  __syncthreads();

  for (int e = tid; e < ucnt; e += 256)
    if (u_sel[e]) {
      const int p = atomicAdd(&s_emit, 1);
      if (p < K_SPARSE) rowlist[p] = make_int2(u_idx[e], __float_as_int(fmaxf((float)u_val[e], 0.0f)));
    }
  __syncthreads();
  if (tid == 0)
    for (int p = s_emit; p < K_SPARSE; ++p) rowlist[p] = make_int2(-1, 0);
}

// ---------- mem-path top-k write: zero + scatter via LDS span ----------
__global__ __launch_bounds__(256) void topk_write(const int2* __restrict__ lists,
                                                  float* __restrict__ C) {
  const int nseg = D_SPARSE / SEG;              // 6
  const int row = blockIdx.x / nseg;
  const int seg = blockIdx.x % nseg;
  const int lo  = seg * SEG;
  const int tid = threadIdx.x;

  __shared__ float span[SEG];
  const float4 z = {0.0f, 0.0f, 0.0f, 0.0f};
  #pragma unroll
  for (int i = 0; i < SEG/1024; ++i)
    reinterpret_cast<float4*>(span)[tid + i*256] = z;
  __syncthreads();

  if (tid < K_SPARSE) {
    const int2 p = lists[(size_t)row * K_SPARSE + tid];
    const int off = p.x - lo;
    if (off >= 0 && off < SEG) span[off] = __int_as_float(p.y);
  }
  __syncthreads();

  float4* __restrict__ out4 = reinterpret_cast<float4*>(C + (size_t)row * D_SPARSE + lo);
  #pragma unroll
  for (int i = 0; i < SEG/1024; ++i)
    out4[tid + i*256] = reinterpret_cast<const float4*>(span)[tid + i*256];
}

// ---------------------------------------------------------------------------
extern "C" void kernel_launch(void* const* d_in, const int* in_sizes, int n_in,
                              void* d_out, int out_size, void* d_ws, size_t ws_size,
                              hipStream_t stream) {
  const float* h        = (const float*)d_in[0];
  const float* W        = (const float*)d_in[1];
  const float* pre_bias = (const float*)d_in[2];
  const float* enc_bias = (const float*)d_in[3];
  float* C = (float*)d_out;

  const size_t a1_bytes  = (size_t)N_TOKENS * D_MODEL * sizeof(_Float16);   // 50.3 MB
  const size_t b1_bytes  = (size_t)D_SPARSE * D_MODEL * sizeof(_Float16);   // 151.0 MB
  const size_t raw_bytes = (size_t)N_TOKENS * RAWCAP * sizeof(int2);        // 50.3 MB
  const size_t cnt_bytes = (size_t)N_TOKENS * CNTSTR * sizeof(int);         // 512 KB
  const size_t fin_bytes = (size_t)N_TOKENS * K_SPARSE * sizeof(int2);      // 8 MB
  if (ws_size < a1_bytes + b1_bytes) return;

  char* base = (char*)d_ws;
  _Float16* A1 = (_Float16*)base;
  _Float16* B1 = (_Float16*)(base + a1_bytes);

  const bool fused = ws_size >= a1_bytes + b1_bytes + raw_bytes + cnt_bytes + fin_bytes;
  int2* raw    = (int2*)(base + a1_bytes + b1_bytes);
  int*  counts = (int*)(base + a1_bytes + b1_bytes + raw_bytes);
  int2* fin    = (int2*)base;   // mem path only: A1 region is dead post-GEMM

  convert_h_kernel<<<2048, 256, 0, stream>>>(h, pre_bias, A1);
  convert_w_kernel<<<4096, 256, 0, stream>>>(W, B1);
  if (fused) zero_counts_kernel<<<(N_TOKENS*CNTSTR + 255)/256, 256, 0, stream>>>(counts);
  gemm_kernel<<<(N_TOKENS/256) * (D_SPARSE/256), 512, 0, stream>>>(
      A1, B1, enc_bias, C, raw, counts, fused ? 1 : 0);
  if (fused) {
    topk_select_fused<<<N_TOKENS, 256, 0, stream>>>(raw, counts, h, pre_bias, W, enc_bias, C);
  } else {
    topk_select_mem<<<N_TOKENS, 256, 0, stream>>>(C, h, pre_bias, W, enc_bias, fin);
    topk_write<<<N_TOKENS * (D_SPARSE/SEG), 256, 0, stream>>>(fin, C);
  }
}